// Round 1
// baseline (24840.831 us; speedup 1.0000x reference)
//
#include <hip/hip_runtime.h>

// EquivariantConvLayer fused kernel — Round 1: f32 VALU baseline.
// N=20000 nodes, E=640000 edges, D0=64 scalars, D1=32 vectors, H=64.
// Design: lane = edge. Per-edge register arrays (es[64], acc blocks) with
// compile-time indexing; weights read via wave-uniform scalar loads.
// Scatter-mean: atomicAdd into d_out (aggr layout == output layout),
// counts in d_ws, then node kernel applies mean/silu/gate/residual in place.

#define NN 20000
#define EE 640000
#define D0 64
#define D1 32
#define HH 64

__device__ __forceinline__ float silu_f(float x) {
    return x / (1.0f + __expf(-x));
}

// Detect whether edge_index arrived as int64 (high dwords all zero) or int32.
__global__ void detect_idx_kernel(const int* __restrict__ eidx, int* __restrict__ flag) {
    int odd_nz = 0, even_nz = 0;
    for (int k = 0; k < 64; ++k) {
        if (eidx[2 * k + 1] != 0) odd_nz = 1;
        if (eidx[2 * k] != 0) even_nz = 1;
    }
    *flag = (!odd_nz && even_nz) ? 1 : 0;  // 1 => int64
}

__global__ __launch_bounds__(256) void edge_kernel(
    const float* __restrict__ feat0e,
    const float* __restrict__ feat1o,
    const float* __restrict__ edge_attr,
    const float* __restrict__ pos,
    const int* __restrict__ eidx,
    const float* __restrict__ W1, const float* __restrict__ b1,
    const float* __restrict__ W2, const float* __restrict__ b2,
    const float* __restrict__ W3, const float* __restrict__ b3,
    const float* __restrict__ wss,
    const float* __restrict__ wvv,
    const float* __restrict__ wsv,
    const float* __restrict__ wvs,
    const float* __restrict__ wcross,
    const int* __restrict__ i64flag,
    float* __restrict__ out,     // [N,160] accumulators (aggr sums)
    float* __restrict__ counts)  // [N]
{
    const int e = blockIdx.x * 256 + threadIdx.x;  // E % 256 == 0

    int src, dst;
    if (*i64flag) {
        src = (int)((const long long*)eidx)[e];
        dst = (int)((const long long*)eidx)[EE + e];
    } else {
        src = eidx[e];
        dst = eidx[EE + e];
    }

    const float rel0 = pos[dst * 3 + 0] - pos[src * 3 + 0];
    const float rel1 = pos[dst * 3 + 1] - pos[src * 3 + 1];
    const float rel2 = pos[dst * 3 + 2] - pos[src * 3 + 2];

    // ---------------- edge MLP: es = (silu(silu(ea@W1+b1)@W2+b2))@W3+b3 -----
    float h1[HH];
#pragma unroll
    for (int j = 0; j < HH; ++j) h1[j] = b1[j];
    for (int i = 0; i < HH; ++i) {  // runtime i: ea from global, W row uniform
        float a = edge_attr[(size_t)e * HH + i];
        const float* w = W1 + i * HH;
#pragma unroll
        for (int j = 0; j < HH; ++j) h1[j] = fmaf(a, w[j], h1[j]);
    }
#pragma unroll
    for (int j = 0; j < HH; ++j) h1[j] = silu_f(h1[j]);

    float h2[HH];
#pragma unroll
    for (int j = 0; j < HH; ++j) h2[j] = b2[j];
#pragma unroll
    for (int i = 0; i < HH; ++i) {  // unrolled: h1[i] must be compile-time
        float a = h1[i];
        const float* w = W2 + i * HH;
#pragma unroll
        for (int j = 0; j < HH; ++j) h2[j] = fmaf(a, w[j], h2[j]);
    }
#pragma unroll
    for (int j = 0; j < HH; ++j) h2[j] = silu_f(h2[j]);

    float es[HH];
#pragma unroll
    for (int j = 0; j < HH; ++j) es[j] = b3[j];
#pragma unroll
    for (int i = 0; i < HH; ++i) {
        float a = h2[i];
        const float* w = W3 + i * HH;
#pragma unroll
        for (int j = 0; j < HH; ++j) es[j] = fmaf(a, w[j], es[j]);
    }
    // (no activation on final layer)

    // ---------------- dot_vv[d] = v[d,:] . rel ------------------------------
    float dotv[D1];
#pragma unroll
    for (int d = 0; d < D1; ++d) {
        float v0 = feat1o[(size_t)src * (D1 * 3) + d * 3 + 0];
        float v1 = feat1o[(size_t)src * (D1 * 3) + d * 3 + 1];
        float v2 = feat1o[(size_t)src * (D1 * 3) + d * 3 + 2];
        dotv[d] = fmaf(v0, rel0, fmaf(v1, rel1, v2 * rel2));
    }

    // ---------------- msg0e = einsum(s,es,wss) + dotv@wvv, o-blocks of 16 ---
#pragma unroll
    for (int ob = 0; ob < 4; ++ob) {
        const int o0 = ob * 16;
        float acc[16];
#pragma unroll
        for (int j = 0; j < 16; ++j) acc[j] = 0.f;

        // vv contribution
#pragma unroll
        for (int d = 0; d < D1; ++d) {
            const float* w = wvv + d * D0 + o0;
#pragma unroll
            for (int j = 0; j < 16; ++j) acc[j] = fmaf(dotv[d], w[j], acc[j]);
        }
        // ss contribution: sum_{p,h} s[p]*es[h]*wss[p,h,o]
        for (int p = 0; p < D0; ++p) {  // runtime p: uniform W base
            float sval = feat0e[(size_t)src * D0 + p];
            const float* wp = wss + (size_t)p * HH * D0 + o0;
#pragma unroll
            for (int h = 0; h < HH; ++h) {
                float c = sval * es[h];
                const float* w = wp + h * D0;
#pragma unroll
                for (int j = 0; j < 16; ++j) acc[j] = fmaf(c, w[j], acc[j]);
            }
        }
        float* obase = out + (size_t)dst * 160 + o0;
#pragma unroll
        for (int j = 0; j < 16; ++j) atomicAdd(obase + j, acc[j]);
    }

    atomicAdd(counts + dst, 1.0f);

    // ---------------- g[c] = s @ wsv --------------------------------------
    float g[D1];
#pragma unroll
    for (int c = 0; c < D1; ++c) g[c] = 0.f;
    for (int p = 0; p < D0; ++p) {
        float sval = feat0e[(size_t)src * D0 + p];
        const float* w = wsv + p * D1;
#pragma unroll
        for (int c = 0; c < D1; ++c) g[c] = fmaf(sval, w[c], g[c]);
    }

    // ---------------- msg1o: sv + vs + cross --------------------------------
    float acc1[D1 * 3];
#pragma unroll
    for (int c = 0; c < D1; ++c) {
        acc1[c * 3 + 0] = g[c] * rel0;
        acc1[c * 3 + 1] = g[c] * rel1;
        acc1[c * 3 + 2] = g[c] * rel2;
    }

    for (int d = 0; d < D1; ++d) {  // runtime d
        float v0 = feat1o[(size_t)src * (D1 * 3) + d * 3 + 0];
        float v1 = feat1o[(size_t)src * (D1 * 3) + d * 3 + 1];
        float v2 = feat1o[(size_t)src * (D1 * 3) + d * 3 + 2];
        // cross(v[d], rel)
        float cx0 = fmaf(v1, rel2, -v2 * rel1);
        float cx1 = fmaf(v2, rel0, -v0 * rel2);
        float cx2 = fmaf(v0, rel1, -v1 * rel0);
        const float* wd = wvs + (size_t)d * HH * D1;
        const float* wc = wcross + d * D1;
#pragma unroll
        for (int cb = 0; cb < 2; ++cb) {  // c in halves of 16 to bound regs
            float t[16];
#pragma unroll
            for (int cc = 0; cc < 16; ++cc) t[cc] = 0.f;
#pragma unroll
            for (int h = 0; h < HH; ++h) {
                const float* w = wd + h * D1 + cb * 16;
                float ev = es[h];
#pragma unroll
                for (int cc = 0; cc < 16; ++cc) t[cc] = fmaf(ev, w[cc], t[cc]);
            }
#pragma unroll
            for (int cc = 0; cc < 16; ++cc) {
                int c = cb * 16 + cc;
                float tc = t[cc];
                float wcc = wc[c];
                acc1[c * 3 + 0] = fmaf(v0, tc, fmaf(cx0, wcc, acc1[c * 3 + 0]));
                acc1[c * 3 + 1] = fmaf(v1, tc, fmaf(cx1, wcc, acc1[c * 3 + 1]));
                acc1[c * 3 + 2] = fmaf(v2, tc, fmaf(cx2, wcc, acc1[c * 3 + 2]));
            }
        }
    }

    float* obase1 = out + (size_t)dst * 160 + 64;
#pragma unroll
    for (int k = 0; k < D1 * 3; ++k) atomicAdd(obase1 + k, acc1[k]);
}

__global__ __launch_bounds__(64) void node_kernel(
    const float* __restrict__ feat0e,
    const float* __restrict__ feat1o,
    const float* __restrict__ Wg, const float* __restrict__ bg,
    const float* __restrict__ counts,
    float* __restrict__ out)
{
    const int n = blockIdx.x;
    const int lane = threadIdx.x;
    __shared__ float a_lds[D0];
    __shared__ float gate_lds[D1];

    const float inv = 1.0f / fmaxf(counts[n], 1.0f);
    float a = out[(size_t)n * 160 + lane] * inv;  // mean aggr0e
    a_lds[lane] = a;
    __syncthreads();

    out[(size_t)n * 160 + lane] = silu_f(a) + feat0e[(size_t)n * D0 + lane];

    if (lane < D1) {
        float gs = bg[lane];
        for (int p = 0; p < D0; ++p) gs = fmaf(a_lds[p], Wg[p * D1 + lane], gs);
        gate_lds[lane] = silu_f(gs);
    }
    __syncthreads();

    for (int idx = lane; idx < D1 * 3; idx += 64) {
        int c = idx / 3;
        size_t o = (size_t)n * 160 + 64 + idx;
        out[o] = fmaf(out[o] * inv, gate_lds[c], feat1o[(size_t)n * (D1 * 3) + idx]);
    }
}

extern "C" void kernel_launch(void* const* d_in, const int* in_sizes, int n_in,
                              void* d_out, int out_size, void* d_ws, size_t ws_size,
                              hipStream_t stream) {
    const float* feat0e   = (const float*)d_in[0];
    const float* feat1o   = (const float*)d_in[1];
    const float* edge_attr= (const float*)d_in[2];
    const float* pos      = (const float*)d_in[3];
    const int*   eidx     = (const int*)d_in[4];
    const float* W1 = (const float*)d_in[5];
    const float* b1 = (const float*)d_in[6];
    const float* W2 = (const float*)d_in[7];
    const float* b2 = (const float*)d_in[8];
    const float* W3 = (const float*)d_in[9];
    const float* b3 = (const float*)d_in[10];
    const float* wss    = (const float*)d_in[11];
    const float* wvv    = (const float*)d_in[12];
    const float* wsv    = (const float*)d_in[13];
    const float* wvs    = (const float*)d_in[14];
    const float* wcross = (const float*)d_in[15];
    const float* Wg = (const float*)d_in[16];
    const float* bg = (const float*)d_in[17];

    float* out    = (float*)d_out;
    float* counts = (float*)d_ws;                    // N floats
    int*   flag   = (int*)((char*)d_ws + NN * 4);    // 1 int after counts

    hipMemsetAsync(d_out, 0, (size_t)out_size * sizeof(float), stream);
    hipMemsetAsync(d_ws, 0, (size_t)NN * sizeof(float) + 16, stream);

    detect_idx_kernel<<<1, 1, 0, stream>>>(eidx, flag);
    edge_kernel<<<EE / 256, 256, 0, stream>>>(
        feat0e, feat1o, edge_attr, pos, eidx,
        W1, b1, W2, b2, W3, b3,
        wss, wvv, wsv, wvs, wcross,
        flag, out, counts);
    node_kernel<<<NN, 64, 0, stream>>>(feat0e, feat1o, Wg, bg, counts, out);
}

// Round 2
// 1435.032 us; speedup vs baseline: 17.3103x; 17.3103x over previous
//
#include <hip/hip_runtime.h>

// EquivariantConvLayer — Round 2: MFMA (16x16x32 f16) for the tensor-product
// GEMMs, LDS-broadcast VALU MLP, coalesced atomic scatter.
// N=20000, E=640000, D0=64, D1=32, H=64.

#define NN 20000
#define EE 640000
#define D0 64
#define D1 32
#define HH 64

typedef _Float16 half8 __attribute__((ext_vector_type(8)));
typedef float f32x4 __attribute__((ext_vector_type(4)));

__device__ __forceinline__ float silu_f(float x) { return x / (1.0f + __expf(-x)); }
__device__ __forceinline__ _Float16 u2h(unsigned short u) {
    union { unsigned short u; _Float16 h; } c; c.u = u; return c.h;
}

// ---- workspace layout (bytes) ----
#define OFF_CNT  0
#define OFF_FLAG 80000
#define OFF_WSS  81920ull            // 64p x 8frag x 64lane x 8 f16 = 512KB
#define OFF_WVS  606208ull           // 32d x 4frag x 64 x 8 f16 = 128KB
#define OFF_WVV  737280ull           // 4frag x 64 x 8 = 4KB
#define OFF_WSV  741376ull           // 4frag x 64 x 8 = 4KB
#define OFF_WX   745472ull           // 2frag x 64 x 8 = 2KB
#define OFF_ES   747520ull           // E x 64 f16 = 81920000
#define WS_NEED  (747520ull + (unsigned long long)EE * 64 * 2)

// ---------------------------------------------------------------------------
__global__ void detect_idx_kernel(const int* __restrict__ eidx, int* __restrict__ flag) {
    int odd_nz = 0, even_nz = 0;
    for (int k = 0; k < 64; ++k) {
        if (eidx[2 * k + 1] != 0) odd_nz = 1;
        if (eidx[2 * k] != 0) even_nz = 1;
    }
    *flag = (!odd_nz && even_nz) ? 1 : 0;  // 1 => int64
}

// ---------------------------------------------------------------------------
// Permute weights into MFMA B-fragment-linear f16 layout.
// Frag convention (16x16x32): lane l holds B[k=(l>>4)*8+j][n=(l&15)+nf*16],
// frag stored as [fragid][lane][8 f16].
__global__ __launch_bounds__(256) void prep_kernel(
    const float* __restrict__ wss, const float* __restrict__ wvv,
    const float* __restrict__ wsv, const float* __restrict__ wvs,
    const float* __restrict__ wx, char* __restrict__ ws)
{
    int id = blockIdx.x * 256 + threadIdx.x;
    if (id >= 41600) return;
    half8 o;
    _Float16* dst;
    if (id < 32768) {                       // wss: p(64) x frag(8=kf4..nf) x lane
        int p = id >> 9; int frag = (id >> 6) & 7; int l = id & 63;
        int kf = frag >> 2, nf = frag & 3;
        int l4 = l >> 4, l16 = l & 15;
#pragma unroll
        for (int j = 0; j < 8; j++) {
            int h = kf * 32 + l4 * 8 + j, oo = nf * 16 + l16;
            o[j] = (_Float16)wss[((size_t)p * 64 + h) * 64 + oo];
        }
        dst = (_Float16*)(ws + OFF_WSS) + (size_t)id * 8;
    } else if (id < 40960) {                // wvs: d(32) x frag(4=kf2,nf2) x lane
        int i = id - 32768;
        int d = i >> 8; int frag = (i >> 6) & 3; int l = i & 63;
        int kf = frag >> 1, nf = frag & 1;
        int l4 = l >> 4, l16 = l & 15;
#pragma unroll
        for (int j = 0; j < 8; j++) {
            int h = kf * 32 + l4 * 8 + j, c = nf * 16 + l16;
            o[j] = (_Float16)wvs[((size_t)d * 64 + h) * 32 + c];
        }
        dst = (_Float16*)(ws + OFF_WVS) + (size_t)i * 8;
    } else if (id < 41216) {                // wvv: K=32(d), N=64: frag nf(4)
        int i = id - 40960; int nf = i >> 6; int l = i & 63;
        int l4 = l >> 4, l16 = l & 15;
#pragma unroll
        for (int j = 0; j < 8; j++) {
            int d = l4 * 8 + j, oo = nf * 16 + l16;
            o[j] = (_Float16)wvv[d * 64 + oo];
        }
        dst = (_Float16*)(ws + OFF_WVV) + (size_t)i * 8;
    } else if (id < 41472) {                // wsv: K=64(p), N=32: frag kf2,nf2
        int i = id - 41216; int frag = i >> 6; int l = i & 63;
        int kf = frag >> 1, nf = frag & 1;
        int l4 = l >> 4, l16 = l & 15;
#pragma unroll
        for (int j = 0; j < 8; j++) {
            int p = kf * 32 + l4 * 8 + j, c = nf * 16 + l16;
            o[j] = (_Float16)wsv[p * 32 + c];
        }
        dst = (_Float16*)(ws + OFF_WSV) + (size_t)i * 8;
    } else {                                // wcross: K=32(d), N=32: frag nf2
        int i = id - 41472; int nf = i >> 6; int l = i & 63;
        int l4 = l >> 4, l16 = l & 15;
#pragma unroll
        for (int j = 0; j < 8; j++) {
            int d = l4 * 8 + j, c = nf * 16 + l16;
            o[j] = (_Float16)wx[d * 32 + c];
        }
        dst = (_Float16*)(ws + OFF_WX) + (size_t)i * 8;
    }
    *(half8*)dst = o;
}

// ---------------------------------------------------------------------------
// MLP: lane = edge, f32 VALU, W1..W3 staged in LDS (broadcast b128 reads).
__global__ __launch_bounds__(256) void mlp_kernel(
    const float* __restrict__ edge_attr,
    const float* __restrict__ W1, const float* __restrict__ b1,
    const float* __restrict__ W2, const float* __restrict__ b2,
    const float* __restrict__ W3, const float* __restrict__ b3,
    _Float16* __restrict__ es_g)
{
    __shared__ float Wl[3 * 4096];
    for (int t = threadIdx.x; t < 4096; t += 256) {
        Wl[t] = W1[t]; Wl[4096 + t] = W2[t]; Wl[8192 + t] = W3[t];
    }
    __syncthreads();
    const int e = blockIdx.x * 256 + threadIdx.x;

    float h1[64];
#pragma unroll
    for (int j = 0; j < 64; j++) h1[j] = b1[j];
    for (int i4 = 0; i4 < 16; ++i4) {       // runtime loop; input from global
        float4 a4 = *(const float4*)(edge_attr + (size_t)e * 64 + i4 * 4);
        float as[4] = {a4.x, a4.y, a4.z, a4.w};
#pragma unroll
        for (int jj = 0; jj < 4; jj++) {
            float a = as[jj];
            const float4* w4 = (const float4*)(Wl + (size_t)(i4 * 4 + jj) * 64);
#pragma unroll
            for (int j4 = 0; j4 < 16; j4++) {
                float4 w = w4[j4];
                h1[j4 * 4 + 0] = fmaf(a, w.x, h1[j4 * 4 + 0]);
                h1[j4 * 4 + 1] = fmaf(a, w.y, h1[j4 * 4 + 1]);
                h1[j4 * 4 + 2] = fmaf(a, w.z, h1[j4 * 4 + 2]);
                h1[j4 * 4 + 3] = fmaf(a, w.w, h1[j4 * 4 + 3]);
            }
        }
    }
#pragma unroll
    for (int j = 0; j < 64; j++) h1[j] = silu_f(h1[j]);

    float h2[64];
#pragma unroll
    for (int j = 0; j < 64; j++) h2[j] = b2[j];
#pragma unroll
    for (int i = 0; i < 64; i++) {
        float a = h1[i];
        const float4* w4 = (const float4*)(Wl + 4096 + (size_t)i * 64);
#pragma unroll
        for (int j4 = 0; j4 < 16; j4++) {
            float4 w = w4[j4];
            h2[j4 * 4 + 0] = fmaf(a, w.x, h2[j4 * 4 + 0]);
            h2[j4 * 4 + 1] = fmaf(a, w.y, h2[j4 * 4 + 1]);
            h2[j4 * 4 + 2] = fmaf(a, w.z, h2[j4 * 4 + 2]);
            h2[j4 * 4 + 3] = fmaf(a, w.w, h2[j4 * 4 + 3]);
        }
    }
#pragma unroll
    for (int j = 0; j < 64; j++) h2[j] = silu_f(h2[j]);

    float h3[64];
#pragma unroll
    for (int j = 0; j < 64; j++) h3[j] = b3[j];
#pragma unroll
    for (int i = 0; i < 64; i++) {
        float a = h2[i];
        const float4* w4 = (const float4*)(Wl + 8192 + (size_t)i * 64);
#pragma unroll
        for (int j4 = 0; j4 < 16; j4++) {
            float4 w = w4[j4];
            h3[j4 * 4 + 0] = fmaf(a, w.x, h3[j4 * 4 + 0]);
            h3[j4 * 4 + 1] = fmaf(a, w.y, h3[j4 * 4 + 1]);
            h3[j4 * 4 + 2] = fmaf(a, w.z, h3[j4 * 4 + 2]);
            h3[j4 * 4 + 3] = fmaf(a, w.w, h3[j4 * 4 + 3]);
        }
    }
    const size_t ebase = (size_t)e * 64;
#pragma unroll
    for (int c8 = 0; c8 < 8; ++c8) {
        half8 o;
#pragma unroll
        for (int k = 0; k < 8; k++) o[k] = (_Float16)h3[c8 * 8 + k];
        *(half8*)(es_g + ebase + c8 * 8) = o;
    }
}

// ---------------------------------------------------------------------------
// msg0e: per wave 64 edges; acc[4mf][4nf]; K = 64p-chunks(s x es) + dotv chunk.
__global__ __launch_bounds__(256, 2) void msg0e_kernel(
    const float* __restrict__ feat0e,
    const float* __restrict__ feat1o,
    const float* __restrict__ pos,
    const int* __restrict__ eidx,
    const int* __restrict__ i64flag,
    const char* __restrict__ wsp,
    float* __restrict__ out,
    float* __restrict__ counts)
{
    __shared__ unsigned short st[4][4096];   // [64e][64p] f16, 16B-block XOR swizzle
    __shared__ float rell[4][64][4];
    __shared__ int srcl[4][64];
    __shared__ int dstl[4][64];

    const int tid = threadIdx.x, w = tid >> 6, lane = tid & 63;
    const int l4 = lane >> 4, l16 = lane & 15;
    const int e0 = blockIdx.x * 256 + w * 64;

    { // stage idx/rel; count
        int e = e0 + lane; int s_, d_;
        if (*i64flag) { s_ = (int)((const long long*)eidx)[e]; d_ = (int)((const long long*)eidx)[EE + e]; }
        else          { s_ = eidx[e];                          d_ = eidx[EE + e]; }
        srcl[w][lane] = s_; dstl[w][lane] = d_;
        rell[w][lane][0] = pos[d_ * 3 + 0] - pos[s_ * 3 + 0];
        rell[w][lane][1] = pos[d_ * 3 + 1] - pos[s_ * 3 + 1];
        rell[w][lane][2] = pos[d_ * 3 + 2] - pos[s_ * 3 + 2];
        atomicAdd(counts + d_, 1.0f);
    }
    __syncthreads();

    // stage s-tile (gather rows by src), f32 -> f16, swizzled
#pragma unroll
    for (int r4 = 0; r4 < 4; r4++) {
        int row = r4 * 16 + (lane >> 2);
        int ch = lane & 3;
        const float* sp = feat0e + (size_t)srcl[w][row] * 64 + ch * 16;
        float4 f0 = *(const float4*)(sp + 0),  f1 = *(const float4*)(sp + 4);
        float4 f2 = *(const float4*)(sp + 8),  f3 = *(const float4*)(sp + 12);
        half8 h0, h1;
        h0[0]=(_Float16)f0.x; h0[1]=(_Float16)f0.y; h0[2]=(_Float16)f0.z; h0[3]=(_Float16)f0.w;
        h0[4]=(_Float16)f1.x; h0[5]=(_Float16)f1.y; h0[6]=(_Float16)f1.z; h0[7]=(_Float16)f1.w;
        h1[0]=(_Float16)f2.x; h1[1]=(_Float16)f2.y; h1[2]=(_Float16)f2.z; h1[3]=(_Float16)f2.w;
        h1[4]=(_Float16)f3.x; h1[5]=(_Float16)f3.y; h1[6]=(_Float16)f3.z; h1[7]=(_Float16)f3.w;
        int r7 = row & 7, b0 = ch * 2, b1b = ch * 2 + 1;
        *(half8*)&st[w][row * 64 + ((b0 ^ r7) * 8)]  = h0;
        *(half8*)&st[w][row * 64 + ((b1b ^ r7) * 8)] = h1;
    }
    __syncthreads();

    // es fragments (k over h), held for the whole K loop
    const _Float16* es_g = (const _Float16*)(wsp + OFF_ES);
    half8 esf[4][2];
#pragma unroll
    for (int mf = 0; mf < 4; mf++)
#pragma unroll
        for (int kf = 0; kf < 2; kf++)
            esf[mf][kf] = *(const half8*)(es_g + (size_t)(e0 + mf * 16 + l16) * 64 + kf * 32 + l4 * 8);

    f32x4 acc[4][4];
#pragma unroll
    for (int mf = 0; mf < 4; mf++)
#pragma unroll
        for (int nf = 0; nf < 4; nf++) acc[mf][nf] = (f32x4){0.f, 0.f, 0.f, 0.f};

    const half8* wssp = (const half8*)(wsp + OFF_WSS);
    for (int p = 0; p < 64; ++p) {
        half8 bf[2][4];
#pragma unroll
        for (int kf = 0; kf < 2; kf++)
#pragma unroll
            for (int nf = 0; nf < 4; nf++)
                bf[kf][nf] = wssp[(size_t)(p * 8 + kf * 4 + nf) * 64 + lane];
        _Float16 sv[4];
#pragma unroll
        for (int mf = 0; mf < 4; mf++) {
            int row = mf * 16 + l16;
            sv[mf] = u2h(st[w][row * 64 + (((p >> 3) ^ (row & 7)) * 8) + (p & 7)]);
        }
#pragma unroll
        for (int mf = 0; mf < 4; mf++)
#pragma unroll
            for (int kf = 0; kf < 2; kf++) {
                half8 a = esf[mf][kf] * sv[mf];
#pragma unroll
                for (int nf = 0; nf < 4; nf++)
                    acc[mf][nf] = __builtin_amdgcn_mfma_f32_16x16x32_f16(a, bf[kf][nf], acc[mf][nf], 0, 0, 0);
            }
    }

    // dotv chunk: A[e][d] = v[e,d,:].rel[e], B = wvv  (K=32, one MFMA step)
    half8 dvf[4];
#pragma unroll
    for (int mf = 0; mf < 4; mf++) {
        int row = mf * 16 + l16;
        int se = srcl[w][row];
        float r0 = rell[w][row][0], r1 = rell[w][row][1], r2 = rell[w][row][2];
        const float* vp = feat1o + (size_t)se * 96 + l4 * 24;
        float4 A = *(const float4*)(vp + 0),  B = *(const float4*)(vp + 4);
        float4 C = *(const float4*)(vp + 8),  D = *(const float4*)(vp + 12);
        float4 E = *(const float4*)(vp + 16), F = *(const float4*)(vp + 20);
        dvf[mf][0] = (_Float16)(A.x * r0 + A.y * r1 + A.z * r2);
        dvf[mf][1] = (_Float16)(A.w * r0 + B.x * r1 + B.y * r2);
        dvf[mf][2] = (_Float16)(B.z * r0 + B.w * r1 + C.x * r2);
        dvf[mf][3] = (_Float16)(C.y * r0 + C.z * r1 + C.w * r2);
        dvf[mf][4] = (_Float16)(D.x * r0 + D.y * r1 + D.z * r2);
        dvf[mf][5] = (_Float16)(D.w * r0 + E.x * r1 + E.y * r2);
        dvf[mf][6] = (_Float16)(E.z * r0 + E.w * r1 + F.x * r2);
        dvf[mf][7] = (_Float16)(F.y * r0 + F.z * r1 + F.w * r2);
    }
    const half8* wvvp = (const half8*)(wsp + OFF_WVV);
#pragma unroll
    for (int nf = 0; nf < 4; nf++) {
        half8 bvv = wvvp[nf * 64 + lane];
#pragma unroll
        for (int mf = 0; mf < 4; mf++)
            acc[mf][nf] = __builtin_amdgcn_mfma_f32_16x16x32_f16(dvf[mf], bvv, acc[mf][nf], 0, 0, 0);
    }

    // scatter (coalesced: 16 consecutive cols per lane group)
#pragma unroll
    for (int mf = 0; mf < 4; mf++)
#pragma unroll
        for (int reg = 0; reg < 4; reg++) {
            int row = mf * 16 + l4 * 4 + reg;
            int de = dstl[w][row];
            float* ob = out + (size_t)de * 160 + l16;
#pragma unroll
            for (int nf = 0; nf < 4; nf++)
                atomicAdd(ob + nf * 16, acc[mf][nf][reg]);
        }
}

// ---------------------------------------------------------------------------
// msg1o: rows=(x,g,e16) 12 m-frags, N=32 (2 n-frags).
// K = 32 d-chunks (v x es over h) + sv chunk (s x rel over p) + cross chunk (d).
__global__ __launch_bounds__(256, 2) void msg1o_kernel(
    const float* __restrict__ feat0e,
    const float* __restrict__ feat1o,
    const float* __restrict__ pos,
    const int* __restrict__ eidx,
    const int* __restrict__ i64flag,
    const char* __restrict__ wsp,
    float* __restrict__ out)
{
    __shared__ unsigned short vt[4][64 * 104];  // [e][96 f16 + pad] row=208B
    __shared__ float rell[4][64][4];
    __shared__ int srcl[4][64];
    __shared__ int dstl[4][64];

    const int tid = threadIdx.x, w = tid >> 6, lane = tid & 63;
    const int l4 = lane >> 4, l16 = lane & 15;
    const int e0 = blockIdx.x * 256 + w * 64;

    { // stage idx/rel
        int e = e0 + lane; int s_, d_;
        if (*i64flag) { s_ = (int)((const long long*)eidx)[e]; d_ = (int)((const long long*)eidx)[EE + e]; }
        else          { s_ = eidx[e];                          d_ = eidx[EE + e]; }
        srcl[w][lane] = s_; dstl[w][lane] = d_;
        rell[w][lane][0] = pos[d_ * 3 + 0] - pos[s_ * 3 + 0];
        rell[w][lane][1] = pos[d_ * 3 + 1] - pos[s_ * 3 + 1];
        rell[w][lane][2] = pos[d_ * 3 + 2] - pos[s_ * 3 + 2];
    }
    __syncthreads();
    { // stage v tile: lane stages its own edge's v row (96 f32 -> f16)
        const float* vp = feat1o + (size_t)srcl[w][lane] * 96;
#pragma unroll
        for (int blk = 0; blk < 12; blk++) {
            float4 a = *(const float4*)(vp + blk * 8);
            float4 b = *(const float4*)(vp + blk * 8 + 4);
            half8 h;
            h[0]=(_Float16)a.x; h[1]=(_Float16)a.y; h[2]=(_Float16)a.z; h[3]=(_Float16)a.w;
            h[4]=(_Float16)b.x; h[5]=(_Float16)b.y; h[6]=(_Float16)b.z; h[7]=(_Float16)b.w;
            *(half8*)&vt[w][lane * 104 + blk * 8] = h;
        }
    }
    __syncthreads();

    const _Float16* es_g = (const _Float16*)(wsp + OFF_ES);
    half8 esf[4][2];
#pragma unroll
    for (int g = 0; g < 4; g++)
#pragma unroll
        for (int kf = 0; kf < 2; kf++)
            esf[g][kf] = *(const half8*)(es_g + (size_t)(e0 + g * 16 + l16) * 64 + kf * 32 + l4 * 8);

    f32x4 acc[3][4][2];
#pragma unroll
    for (int x = 0; x < 3; x++)
#pragma unroll
        for (int g = 0; g < 4; g++)
#pragma unroll
            for (int nf = 0; nf < 2; nf++) acc[x][g][nf] = (f32x4){0.f, 0.f, 0.f, 0.f};

    // vs path: per d, A[(e,x)][h] = v[e,d,x]*es[e,h], B = wvs[d]
    const half8* wvsp = (const half8*)(wsp + OFF_WVS);
    for (int d = 0; d < 32; ++d) {
        half8 bf[2][2];
#pragma unroll
        for (int kf = 0; kf < 2; kf++)
#pragma unroll
            for (int nf = 0; nf < 2; nf++)
                bf[kf][nf] = wvsp[(size_t)(d * 4 + kf * 2 + nf) * 64 + lane];
        _Float16 v16[3][4];
#pragma unroll
        for (int g = 0; g < 4; g++) {
            int e = g * 16 + l16;
#pragma unroll
            for (int x = 0; x < 3; x++) v16[x][g] = u2h(vt[w][e * 104 + d * 3 + x]);
        }
#pragma unroll
        for (int x = 0; x < 3; x++)
#pragma unroll
            for (int g = 0; g < 4; g++)
#pragma unroll
                for (int kf = 0; kf < 2; kf++) {
                    half8 a = esf[g][kf] * v16[x][g];
#pragma unroll
                    for (int nf = 0; nf < 2; nf++)
                        acc[x][g][nf] = __builtin_amdgcn_mfma_f32_16x16x32_f16(a, bf[kf][nf], acc[x][g][nf], 0, 0, 0);
                }
    }

    // sv path: A[(e,x)][p] = s[e,p]*rel[e,x], B = wsv
    {
        const half8* wsvp = (const half8*)(wsp + OFF_WSV);
        half8 bsv[2][2];
#pragma unroll
        for (int kf = 0; kf < 2; kf++)
#pragma unroll
            for (int nf = 0; nf < 2; nf++)
                bsv[kf][nf] = wsvp[(size_t)(kf * 2 + nf) * 64 + lane];
        half8 sf[4][2];
#pragma unroll
        for (int g = 0; g < 4; g++) {
            int row = g * 16 + l16;
            const float* sp = feat0e + (size_t)srcl[w][row] * 64 + l4 * 8;
#pragma unroll
            for (int kf = 0; kf < 2; kf++) {
                float4 a = *(const float4*)(sp + kf * 32);
                float4 b = *(const float4*)(sp + kf * 32 + 4);
                half8 h;
                h[0]=(_Float16)a.x; h[1]=(_Float16)a.y; h[2]=(_Float16)a.z; h[3]=(_Float16)a.w;
                h[4]=(_Float16)b.x; h[5]=(_Float16)b.y; h[6]=(_Float16)b.z; h[7]=(_Float16)b.w;
                sf[g][kf] = h;
            }
        }
#pragma unroll
        for (int x = 0; x < 3; x++)
#pragma unroll
            for (int g = 0; g < 4; g++) {
                _Float16 rl = (_Float16)rell[w][g * 16 + l16][x];
#pragma unroll
                for (int kf = 0; kf < 2; kf++) {
                    half8 a = sf[g][kf] * rl;
#pragma unroll
                    for (int nf = 0; nf < 2; nf++)
                        acc[x][g][nf] = __builtin_amdgcn_mfma_f32_16x16x32_f16(a, bsv[kf][nf], acc[x][g][nf], 0, 0, 0);
                }
            }
    }

    // cross path: A[(e,x)][d] = cross(v,rel)[d,x] = v[x1]*r[x2]-v[x2]*r[x1]
    {
        const half8* wxp = (const half8*)(wsp + OFF_WX);
        half8 bx[2];
        bx[0] = wxp[0 * 64 + lane];
        bx[1] = wxp[1 * 64 + lane];
#pragma unroll
        for (int x = 0; x < 3; x++) {
            const int x1 = (x + 1) % 3, x2 = (x + 2) % 3;
#pragma unroll
            for (int g = 0; g < 4; g++) {
                int e = g * 16 + l16;
                float r1 = rell[w][e][x1], r2 = rell[w][e][x2];
                half8 cf;
#pragma unroll
                for (int j = 0; j < 8; j++) {
                    int d = l4 * 8 + j;
                    float vy = (float)u2h(vt[w][e * 104 + d * 3 + x1]);
                    float vz = (float)u2h(vt[w][e * 104 + d * 3 + x2]);
                    cf[j] = (_Float16)(vy * r2 - vz * r1);
                }
#pragma unroll
                for (int nf = 0; nf < 2; nf++)
                    acc[x][g][nf] = __builtin_amdgcn_mfma_f32_16x16x32_f16(cf, bx[nf], acc[x][g][nf], 0, 0, 0);
            }
        }
    }

    // scatter: out[dst][64 + c*3 + x]
#pragma unroll
    for (int x = 0; x < 3; x++)
#pragma unroll
        for (int g = 0; g < 4; g++)
#pragma unroll
            for (int nf = 0; nf < 2; nf++)
#pragma unroll
                for (int reg = 0; reg < 4; reg++) {
                    int row = g * 16 + l4 * 4 + reg;
                    int de = dstl[w][row];
                    atomicAdd(out + (size_t)de * 160 + 64 + (nf * 16 + l16) * 3 + x,
                              acc[x][g][nf][reg]);
                }
}

// ---------------------------------------------------------------------------
__global__ __launch_bounds__(64) void node_kernel(
    const float* __restrict__ feat0e,
    const float* __restrict__ feat1o,
    const float* __restrict__ Wg, const float* __restrict__ bg,
    const float* __restrict__ counts,
    float* __restrict__ out)
{
    const int n = blockIdx.x;
    const int lane = threadIdx.x;
    __shared__ float a_lds[D0];
    __shared__ float gate_lds[D1];

    const float inv = 1.0f / fmaxf(counts[n], 1.0f);
    float a = out[(size_t)n * 160 + lane] * inv;
    a_lds[lane] = a;
    __syncthreads();

    out[(size_t)n * 160 + lane] = silu_f(a) + feat0e[(size_t)n * D0 + lane];

    if (lane < D1) {
        float gs = bg[lane];
        for (int p = 0; p < D0; ++p) gs = fmaf(a_lds[p], Wg[p * D1 + lane], gs);
        gate_lds[lane] = silu_f(gs);
    }
    __syncthreads();

    for (int idx = lane; idx < D1 * 3; idx += 64) {
        int c = idx / 3;
        size_t o = (size_t)n * 160 + 64 + idx;
        out[o] = fmaf(out[o] * inv, gate_lds[c], feat1o[(size_t)n * (D1 * 3) + idx]);
    }
}

// ---------------------------------------------------------------------------
// Fallback (round-1 monolithic VALU kernel) for small ws_size.
__global__ __launch_bounds__(256) void edge_kernel_fb(
    const float* __restrict__ feat0e, const float* __restrict__ feat1o,
    const float* __restrict__ edge_attr, const float* __restrict__ pos,
    const int* __restrict__ eidx,
    const float* __restrict__ W1, const float* __restrict__ b1,
    const float* __restrict__ W2, const float* __restrict__ b2,
    const float* __restrict__ W3, const float* __restrict__ b3,
    const float* __restrict__ wss, const float* __restrict__ wvv,
    const float* __restrict__ wsv, const float* __restrict__ wvs,
    const float* __restrict__ wcross,
    const int* __restrict__ i64flag,
    float* __restrict__ out, float* __restrict__ counts)
{
    const int e = blockIdx.x * 256 + threadIdx.x;
    int src, dst;
    if (*i64flag) { src = (int)((const long long*)eidx)[e]; dst = (int)((const long long*)eidx)[EE + e]; }
    else          { src = eidx[e];                          dst = eidx[EE + e]; }
    const float rel0 = pos[dst * 3 + 0] - pos[src * 3 + 0];
    const float rel1 = pos[dst * 3 + 1] - pos[src * 3 + 1];
    const float rel2 = pos[dst * 3 + 2] - pos[src * 3 + 2];
    float h1[HH];
#pragma unroll
    for (int j = 0; j < HH; ++j) h1[j] = b1[j];
    for (int i = 0; i < HH; ++i) {
        float a = edge_attr[(size_t)e * HH + i];
        const float* ww = W1 + i * HH;
#pragma unroll
        for (int j = 0; j < HH; ++j) h1[j] = fmaf(a, ww[j], h1[j]);
    }
#pragma unroll
    for (int j = 0; j < HH; ++j) h1[j] = silu_f(h1[j]);
    float h2[HH];
#pragma unroll
    for (int j = 0; j < HH; ++j) h2[j] = b2[j];
#pragma unroll
    for (int i = 0; i < HH; ++i) {
        float a = h1[i];
        const float* ww = W2 + i * HH;
#pragma unroll
        for (int j = 0; j < HH; ++j) h2[j] = fmaf(a, ww[j], h2[j]);
    }
#pragma unroll
    for (int j = 0; j < HH; ++j) h2[j] = silu_f(h2[j]);
    float es[HH];
#pragma unroll
    for (int j = 0; j < HH; ++j) es[j] = b3[j];
#pragma unroll
    for (int i = 0; i < HH; ++i) {
        float a = h2[i];
        const float* ww = W3 + i * HH;
#pragma unroll
        for (int j = 0; j < HH; ++j) es[j] = fmaf(a, ww[j], es[j]);
    }
    float dotv[D1];
#pragma unroll
    for (int d = 0; d < D1; ++d) {
        float v0 = feat1o[(size_t)src * 96 + d * 3 + 0];
        float v1 = feat1o[(size_t)src * 96 + d * 3 + 1];
        float v2 = feat1o[(size_t)src * 96 + d * 3 + 2];
        dotv[d] = fmaf(v0, rel0, fmaf(v1, rel1, v2 * rel2));
    }
#pragma unroll
    for (int ob = 0; ob < 4; ++ob) {
        const int o0 = ob * 16;
        float acc[16];
#pragma unroll
        for (int j = 0; j < 16; ++j) acc[j] = 0.f;
#pragma unroll
        for (int d = 0; d < D1; ++d) {
            const float* ww = wvv + d * D0 + o0;
#pragma unroll
            for (int j = 0; j < 16; ++j) acc[j] = fmaf(dotv[d], ww[j], acc[j]);
        }
        for (int p = 0; p < D0; ++p) {
            float sval = feat0e[(size_t)src * D0 + p];
            const float* wp = wss + (size_t)p * HH * D0 + o0;
#pragma unroll
            for (int h = 0; h < HH; ++h) {
                float c = sval * es[h];
                const float* ww = wp + h * D0;
#pragma unroll
                for (int j = 0; j < 16; ++j) acc[j] = fmaf(c, ww[j], acc[j]);
            }
        }
        float* obase = out + (size_t)dst * 160 + o0;
#pragma unroll
        for (int j = 0; j < 16; ++j) atomicAdd(obase + j, acc[j]);
    }
    atomicAdd(counts + dst, 1.0f);
    float g[D1];
#pragma unroll
    for (int c = 0; c < D1; ++c) g[c] = 0.f;
    for (int p = 0; p < D0; ++p) {
        float sval = feat0e[(size_t)src * D0 + p];
        const float* ww = wsv + p * D1;
#pragma unroll
        for (int c = 0; c < D1; ++c) g[c] = fmaf(sval, ww[c], g[c]);
    }
    float acc1[D1 * 3];
#pragma unroll
    for (int c = 0; c < D1; ++c) {
        acc1[c * 3 + 0] = g[c] * rel0;
        acc1[c * 3 + 1] = g[c] * rel1;
        acc1[c * 3 + 2] = g[c] * rel2;
    }
    for (int d = 0; d < D1; ++d) {
        float v0 = feat1o[(size_t)src * 96 + d * 3 + 0];
        float v1 = feat1o[(size_t)src * 96 + d * 3 + 1];
        float v2 = feat1o[(size_t)src * 96 + d * 3 + 2];
        float cx0 = fmaf(v1, rel2, -v2 * rel1);
        float cx1 = fmaf(v2, rel0, -v0 * rel2);
        float cx2 = fmaf(v0, rel1, -v1 * rel0);
        const float* wd = wvs + (size_t)d * HH * D1;
        const float* wc = wcross + d * D1;
#pragma unroll
        for (int cb = 0; cb < 2; ++cb) {
            float t[16];
#pragma unroll
            for (int cc = 0; cc < 16; ++cc) t[cc] = 0.f;
#pragma unroll
            for (int h = 0; h < HH; ++h) {
                const float* ww = wd + h * D1 + cb * 16;
                float ev = es[h];
#pragma unroll
                for (int cc = 0; cc < 16; ++cc) t[cc] = fmaf(ev, ww[cc], t[cc]);
            }
#pragma unroll
            for (int cc = 0; cc < 16; ++cc) {
                int c = cb * 16 + cc;
                float tc = t[cc], wcc = wc[c];
                acc1[c * 3 + 0] = fmaf(v0, tc, fmaf(cx0, wcc, acc1[c * 3 + 0]));
                acc1[c * 3 + 1] = fmaf(v1, tc, fmaf(cx1, wcc, acc1[c * 3 + 1]));
                acc1[c * 3 + 2] = fmaf(v2, tc, fmaf(cx2, wcc, acc1[c * 3 + 2]));
            }
        }
    }
    float* obase1 = out + (size_t)dst * 160 + 64;
#pragma unroll
    for (int k = 0; k < D1 * 3; ++k) atomicAdd(obase1 + k, acc1[k]);
}

// ---------------------------------------------------------------------------
extern "C" void kernel_launch(void* const* d_in, const int* in_sizes, int n_in,
                              void* d_out, int out_size, void* d_ws, size_t ws_size,
                              hipStream_t stream) {
    const float* feat0e    = (const float*)d_in[0];
    const float* feat1o    = (const float*)d_in[1];
    const float* edge_attr = (const float*)d_in[2];
    const float* pos       = (const float*)d_in[3];
    const int*   eidx      = (const int*)d_in[4];
    const float* W1 = (const float*)d_in[5];
    const float* b1 = (const float*)d_in[6];
    const float* W2 = (const float*)d_in[7];
    const float* b2 = (const float*)d_in[8];
    const float* W3 = (const float*)d_in[9];
    const float* b3 = (const float*)d_in[10];
    const float* wss    = (const float*)d_in[11];
    const float* wvv    = (const float*)d_in[12];
    const float* wsv    = (const float*)d_in[13];
    const float* wvs    = (const float*)d_in[14];
    const float* wcross = (const float*)d_in[15];
    const float* Wg = (const float*)d_in[16];
    const float* bg = (const float*)d_in[17];

    float* out    = (float*)d_out;
    char*  ws     = (char*)d_ws;
    float* counts = (float*)(ws + OFF_CNT);
    int*   flag   = (int*)(ws + OFF_FLAG);

    hipMemsetAsync(d_out, 0, (size_t)out_size * sizeof(float), stream);
    hipMemsetAsync(d_ws, 0, 80064, stream);

    detect_idx_kernel<<<1, 1, 0, stream>>>(eidx, flag);

    if (ws_size >= WS_NEED) {
        _Float16* es_g = (_Float16*)(ws + OFF_ES);
        prep_kernel<<<163, 256, 0, stream>>>(wss, wvv, wsv, wvs, wcross, ws);
        mlp_kernel<<<EE / 256, 256, 0, stream>>>(edge_attr, W1, b1, W2, b2, W3, b3, es_g);
        msg0e_kernel<<<EE / 256, 256, 0, stream>>>(feat0e, feat1o, pos, eidx, flag,
                                                   (const char*)ws, out, counts);
        msg1o_kernel<<<EE / 256, 256, 0, stream>>>(feat0e, feat1o, pos, eidx, flag,
                                                   (const char*)ws, out);
    } else {
        edge_kernel_fb<<<EE / 256, 256, 0, stream>>>(
            feat0e, feat1o, edge_attr, pos, eidx,
            W1, b1, W2, b2, W3, b3, wss, wvv, wsv, wvs, wcross,
            flag, out, counts);
    }
    node_kernel<<<NN, 64, 0, stream>>>(feat0e, feat1o, Wg, bg, counts, out);
}

// Round 3
// 1094.673 us; speedup vs baseline: 22.6925x; 1.3109x over previous
//
#include <hip/hip_runtime.h>

// EquivariantConvLayer — Round 3.
// msg1o re-factored: T = es@wvs2 via MFMA (512 MFMA/wave vs 1536), VALU consume
// with v from conflict-free [d][x][e] LDS tile; cross via CX = v@wx MFMA.
// MLP moved to MFMA (prep-permuted weight frags + swizzled LDS exchange).
// msg0e: kf-split B loads, unroll-2, launch_bounds(256,3).

#define NN 20000
#define EE 640000
#define D0 64
#define D1 32
#define HH 64

typedef _Float16 half8 __attribute__((ext_vector_type(8)));
typedef _Float16 half4 __attribute__((ext_vector_type(4)));
typedef float f32x4 __attribute__((ext_vector_type(4)));

__device__ __forceinline__ float silu_f(float x) { return x / (1.0f + __expf(-x)); }
__device__ __forceinline__ _Float16 u2h(unsigned short u) {
    union { unsigned short u; _Float16 h; } c; c.u = u; return c.h;
}
__device__ __forceinline__ unsigned short h2u(_Float16 h) {
    union { unsigned short u; _Float16 h; } c; c.h = h; return c.u;
}

// ---- workspace layout (bytes) ----
#define OFF_CNT   0
#define OFF_FLAG  80000
#define OFF_WSS   81920ull      // 64p x 8frag x 64lane x half8 = 512KB
#define OFF_WVS2  606208ull     // 128frag x 64 x half8 = 128KB   (T-scheme B)
#define OFF_WVV   737280ull     // 4frag x 64 x half8 = 4KB
#define OFF_WSV   741376ull     // 4frag x 64 x half8 = 4KB
#define OFF_WX    745472ull     // 2frag x 64 x half8 = 2KB
#define OFF_WMLP  747520ull     // 24frag x 64 x half8 = 24KB
#define OFF_ES    772096ull     // E x 64 f16
#define WS_NEED   (772096ull + (unsigned long long)EE * 64 * 2)

// ---------------------------------------------------------------------------
__global__ void detect_idx_kernel(const int* __restrict__ eidx, int* __restrict__ flag) {
    int odd_nz = 0, even_nz = 0;
    for (int k = 0; k < 64; ++k) {
        if (eidx[2 * k + 1] != 0) odd_nz = 1;
        if (eidx[2 * k] != 0) even_nz = 1;
    }
    *flag = (!odd_nz && even_nz) ? 1 : 0;  // 1 => int64
}

// ---------------------------------------------------------------------------
// Permute weights into MFMA fragment-linear f16 layouts.
// B-frag convention (16x16x32, HW-verified round 2): lane l holds
// B[k=kf*32+(l>>4)*8+j][n=nf*16+(l&15)], frag stored [fragid][lane][half8].
__global__ __launch_bounds__(256) void prep_kernel(
    const float* __restrict__ wss, const float* __restrict__ wvv,
    const float* __restrict__ wsv, const float* __restrict__ wvs,
    const float* __restrict__ wx,
    const float* __restrict__ W1, const float* __restrict__ W2,
    const float* __restrict__ W3, char* __restrict__ ws)
{
    int id = blockIdx.x * 256 + threadIdx.x;
    if (id >= 43136) return;
    int l = id & 63;
    int l4 = l >> 4, l16 = l & 15;
    half8 o;
    _Float16* dst;
    if (id < 32768) {                       // wss: p(64) x frag(8 = kf*4+nf)
        int p = id >> 9; int frag = (id >> 6) & 7;
        int kf = frag >> 2, nf = frag & 3;
#pragma unroll
        for (int j = 0; j < 8; j++) {
            int h = kf * 32 + l4 * 8 + j, oo = nf * 16 + l16;
            o[j] = (_Float16)wss[((size_t)p * 64 + h) * 64 + oo];
        }
        dst = (_Float16*)(ws + OFF_WSS) + (size_t)id * 8;
    } else if (id < 40960) {                // wvs2: B[h][col=d*32+c], 128 frags
        int i = id - 32768;
        int f = i >> 6;                      // chunk*8 + kf*4 + nfl
        int chunk = f >> 3, kf = (f >> 2) & 1, nfl = f & 3;
#pragma unroll
        for (int j = 0; j < 8; j++) {
            int h = kf * 32 + l4 * 8 + j;
            int col = chunk * 64 + nfl * 16 + l16;
            int d = col >> 5, c = col & 31;
            o[j] = (_Float16)wvs[((size_t)d * 64 + h) * 32 + c];
        }
        dst = (_Float16*)(ws + OFF_WVS2) + (size_t)i * 8;
    } else if (id < 41216) {                // wvv: K=32(d), N=64
        int i = id - 40960; int nf = i >> 6;
#pragma unroll
        for (int j = 0; j < 8; j++) {
            int d = l4 * 8 + j, oo = nf * 16 + l16;
            o[j] = (_Float16)wvv[d * 64 + oo];
        }
        dst = (_Float16*)(ws + OFF_WVV) + (size_t)i * 8;
    } else if (id < 41472) {                // wsv: K=64(p), N=32
        int i = id - 41216; int frag = i >> 6;
        int kf = frag >> 1, nf = frag & 1;
#pragma unroll
        for (int j = 0; j < 8; j++) {
            int p = kf * 32 + l4 * 8 + j, c = nf * 16 + l16;
            o[j] = (_Float16)wsv[p * 32 + c];
        }
        dst = (_Float16*)(ws + OFF_WSV) + (size_t)i * 8;
    } else if (id < 41600) {                // wcross: K=32(d), N=32
        int i = id - 41472; int nf = i >> 6;
#pragma unroll
        for (int j = 0; j < 8; j++) {
            int d = l4 * 8 + j, c = nf * 16 + l16;
            o[j] = (_Float16)wx[d * 32 + c];
        }
        dst = (_Float16*)(ws + OFF_WX) + (size_t)i * 8;
    } else {                                // W1..W3: K=64, N=64, 8 frags each
        int i = id - 41600; int f = i >> 6;
        int layer = f >> 3, kf = (f >> 2) & 1, nf = f & 3;
        const float* W = layer == 0 ? W1 : (layer == 1 ? W2 : W3);
#pragma unroll
        for (int j = 0; j < 8; j++) {
            int r = kf * 32 + l4 * 8 + j, cc = nf * 16 + l16;
            o[j] = (_Float16)W[r * 64 + cc];
        }
        dst = (_Float16*)(ws + OFF_WMLP) + (size_t)i * 8;
    }
    *(half8*)dst = o;
}

// ---------------------------------------------------------------------------
// MLP via MFMA: 3 x [64e,64]@[64,64] per wave, silu between, es -> ws (f16).
__global__ __launch_bounds__(256, 2) void mlp_kernel(
    const float* __restrict__ edge_attr,
    const float* __restrict__ b1, const float* __restrict__ b2,
    const float* __restrict__ b3,
    const char* __restrict__ wsp, _Float16* __restrict__ es_g)
{
    __shared__ unsigned short Wf[24 * 64 * 8];   // 24 weight frags
    __shared__ unsigned short xg[4][64 * 64];    // per-wave exchange (swizzled)
    const int tid = threadIdx.x, w = tid >> 6, lane = tid & 63;
    const int l4 = lane >> 4, l16 = lane & 15;
    const int e0 = blockIdx.x * 256 + w * 64;

    {
        const half8* wm = (const half8*)(wsp + OFF_WMLP);
        for (int f = tid; f < 1536; f += 256) ((half8*)Wf)[f] = wm[f];
    }
    __syncthreads();

    float bias[3][4];
#pragma unroll
    for (int nf = 0; nf < 4; nf++) {
        bias[0][nf] = b1[nf * 16 + l16];
        bias[1][nf] = b2[nf * 16 + l16];
        bias[2][nf] = b3[nf * 16 + l16];
    }

    // A0 frags straight from global
    half8 af[4][2];
#pragma unroll
    for (int mf = 0; mf < 4; mf++)
#pragma unroll
        for (int kf = 0; kf < 2; kf++) {
            const float* p = edge_attr + (size_t)(e0 + mf * 16 + l16) * 64 + kf * 32 + l4 * 8;
            float4 a = *(const float4*)p, b = *(const float4*)(p + 4);
            half8 h;
            h[0]=(_Float16)a.x; h[1]=(_Float16)a.y; h[2]=(_Float16)a.z; h[3]=(_Float16)a.w;
            h[4]=(_Float16)b.x; h[5]=(_Float16)b.y; h[6]=(_Float16)b.z; h[7]=(_Float16)b.w;
            af[mf][kf] = h;
        }

    const half8* wfr = (const half8*)Wf;
#pragma unroll 1
    for (int layer = 0; layer < 3; ++layer) {
        f32x4 acc[4][4];
#pragma unroll
        for (int mf = 0; mf < 4; mf++)
#pragma unroll
            for (int nf = 0; nf < 4; nf++) acc[mf][nf] = (f32x4){0.f,0.f,0.f,0.f};
#pragma unroll
        for (int kf = 0; kf < 2; kf++)
#pragma unroll
            for (int mf = 0; mf < 4; mf++)
#pragma unroll
                for (int nf = 0; nf < 4; nf++)
                    acc[mf][nf] = __builtin_amdgcn_mfma_f32_16x16x32_f16(
                        af[mf][kf], wfr[(layer * 8 + kf * 4 + nf) * 64 + lane],
                        acc[mf][nf], 0, 0, 0);
        // bias (+silu except last), write to swizzled exchange
#pragma unroll
        for (int mf = 0; mf < 4; mf++)
#pragma unroll
            for (int nf = 0; nf < 4; nf++)
#pragma unroll
                for (int reg = 0; reg < 4; reg++) {
                    int row = mf * 16 + l4 * 4 + reg;
                    int col = nf * 16 + l16;
                    float v = acc[mf][nf][reg] + bias[layer][nf];
                    if (layer < 2) v = silu_f(v);
                    xg[w][row * 64 + (col ^ ((row & 7) << 3))] = h2u((_Float16)v);
                }
        if (layer < 2) {
            // read back as A frags (swizzle-consistent, conflict-free)
#pragma unroll
            for (int mf = 0; mf < 4; mf++)
#pragma unroll
                for (int kf = 0; kf < 2; kf++) {
                    int row = mf * 16 + l16;
                    int cs = kf * 32 + l4 * 8;
                    af[mf][kf] = *(const half8*)&xg[w][row * 64 + (cs ^ ((row & 7) << 3))];
                }
        }
    }
    // coalesced store of es tile
#pragma unroll
    for (int t = 0; t < 8; t++) {
        int row = t * 8 + (lane >> 3);
        int cs = (lane & 7) * 8;
        half8 v = *(const half8*)&xg[w][row * 64 + (cs ^ ((row & 7) << 3))];
        *(half8*)(es_g + (size_t)(e0 + row) * 64 + cs) = v;
    }
}

// ---------------------------------------------------------------------------
// msg0e: per wave 64 edges; acc[4mf][4nf]; K = 64p chunks (s x es) + dotv.
__global__ __launch_bounds__(256, 3) void msg0e_kernel(
    const float* __restrict__ feat0e,
    const float* __restrict__ feat1o,
    const float* __restrict__ pos,
    const int* __restrict__ eidx,
    const int* __restrict__ i64flag,
    const char* __restrict__ wsp,
    float* __restrict__ out,
    float* __restrict__ counts)
{
    __shared__ unsigned short st[4][4096];   // [64e][64p] f16, 16B-block XOR swizzle
    __shared__ float rell[4][64][4];
    __shared__ int srcl[4][64];
    __shared__ int dstl[4][64];

    const int tid = threadIdx.x, w = tid >> 6, lane = tid & 63;
    const int l4 = lane >> 4, l16 = lane & 15;
    const int e0 = blockIdx.x * 256 + w * 64;

    { // stage idx/rel; count
        int e = e0 + lane; int s_, d_;
        if (*i64flag) { s_ = (int)((const long long*)eidx)[e]; d_ = (int)((const long long*)eidx)[EE + e]; }
        else          { s_ = eidx[e];                          d_ = eidx[EE + e]; }
        srcl[w][lane] = s_; dstl[w][lane] = d_;
        rell[w][lane][0] = pos[d_ * 3 + 0] - pos[s_ * 3 + 0];
        rell[w][lane][1] = pos[d_ * 3 + 1] - pos[s_ * 3 + 1];
        rell[w][lane][2] = pos[d_ * 3 + 2] - pos[s_ * 3 + 2];
        atomicAdd(counts + d_, 1.0f);
    }
    __syncthreads();

    // stage s-tile (gather by src), f32 -> f16, swizzled
#pragma unroll
    for (int r4 = 0; r4 < 4; r4++) {
        int row = r4 * 16 + (lane >> 2);
        int ch = lane & 3;
        const float* sp = feat0e + (size_t)srcl[w][row] * 64 + ch * 16;
        float4 f0 = *(const float4*)(sp + 0),  f1 = *(const float4*)(sp + 4);
        float4 f2 = *(const float4*)(sp + 8),  f3 = *(const float4*)(sp + 12);
        half8 h0, h1;
        h0[0]=(_Float16)f0.x; h0[1]=(_Float16)f0.y; h0[2]=(_Float16)f0.z; h0[3]=(_Float16)f0.w;
        h0[4]=(_Float16)f1.x; h0[5]=(_Float16)f1.y; h0[6]=(_Float16)f1.z; h0[7]=(_Float16)f1.w;
        h1[0]=(_Float16)f2.x; h1[1]=(_Float16)f2.y; h1[2]=(_Float16)f2.z; h1[3]=(_Float16)f2.w;
        h1[4]=(_Float16)f3.x; h1[5]=(_Float16)f3.y; h1[6]=(_Float16)f3.z; h1[7]=(_Float16)f3.w;
        int r7 = row & 7, b0 = ch * 2, b1b = ch * 2 + 1;
        *(half8*)&st[w][row * 64 + ((b0 ^ r7) * 8)]  = h0;
        *(half8*)&st[w][row * 64 + ((b1b ^ r7) * 8)] = h1;
    }
    __syncthreads();

    const _Float16* es_g = (const _Float16*)(wsp + OFF_ES);
    half8 esf[4][2];
#pragma unroll
    for (int mf = 0; mf < 4; mf++)
#pragma unroll
        for (int kf = 0; kf < 2; kf++)
            esf[mf][kf] = *(const half8*)(es_g + (size_t)(e0 + mf * 16 + l16) * 64 + kf * 32 + l4 * 8);

    f32x4 acc[4][4];
#pragma unroll
    for (int mf = 0; mf < 4; mf++)
#pragma unroll
        for (int nf = 0; nf < 4; nf++) acc[mf][nf] = (f32x4){0.f, 0.f, 0.f, 0.f};

    const half8* wssp = (const half8*)(wsp + OFF_WSS);
#pragma unroll 2
    for (int p = 0; p < 64; ++p) {
        _Float16 sv[4];
#pragma unroll
        for (int mf = 0; mf < 4; mf++) {
            int row = mf * 16 + l16;
            sv[mf] = u2h(st[w][row * 64 + (((p >> 3) ^ (row & 7)) * 8) + (p & 7)]);
        }
#pragma unroll
        for (int kf = 0; kf < 2; kf++) {
            half8 bf[4];
#pragma unroll
            for (int nf = 0; nf < 4; nf++)
                bf[nf] = wssp[(size_t)(p * 8 + kf * 4 + nf) * 64 + lane];
#pragma unroll
            for (int mf = 0; mf < 4; mf++) {
                half8 a = esf[mf][kf] * sv[mf];
#pragma unroll
                for (int nf = 0; nf < 4; nf++)
                    acc[mf][nf] = __builtin_amdgcn_mfma_f32_16x16x32_f16(a, bf[nf], acc[mf][nf], 0, 0, 0);
            }
        }
    }

    // dotv chunk
    half8 dvf[4];
#pragma unroll
    for (int mf = 0; mf < 4; mf++) {
        int row = mf * 16 + l16;
        int se = srcl[w][row];
        float r0 = rell[w][row][0], r1 = rell[w][row][1], r2 = rell[w][row][2];
        const float* vp = feat1o + (size_t)se * 96 + l4 * 24;
        float4 A = *(const float4*)(vp + 0),  B = *(const float4*)(vp + 4);
        float4 C = *(const float4*)(vp + 8),  D = *(const float4*)(vp + 12);
        float4 E = *(const float4*)(vp + 16), F = *(const float4*)(vp + 20);
        dvf[mf][0] = (_Float16)(A.x * r0 + A.y * r1 + A.z * r2);
        dvf[mf][1] = (_Float16)(A.w * r0 + B.x * r1 + B.y * r2);
        dvf[mf][2] = (_Float16)(B.z * r0 + B.w * r1 + C.x * r2);
        dvf[mf][3] = (_Float16)(C.y * r0 + C.z * r1 + C.w * r2);
        dvf[mf][4] = (_Float16)(D.x * r0 + D.y * r1 + D.z * r2);
        dvf[mf][5] = (_Float16)(D.w * r0 + E.x * r1 + E.y * r2);
        dvf[mf][6] = (_Float16)(E.z * r0 + E.w * r1 + F.x * r2);
        dvf[mf][7] = (_Float16)(F.y * r0 + F.z * r1 + F.w * r2);
    }
    const half8* wvvp = (const half8*)(wsp + OFF_WVV);
#pragma unroll
    for (int nf = 0; nf < 4; nf++) {
        half8 bvv = wvvp[nf * 64 + lane];
#pragma unroll
        for (int mf = 0; mf < 4; mf++)
            acc[mf][nf] = __builtin_amdgcn_mfma_f32_16x16x32_f16(dvf[mf], bvv, acc[mf][nf], 0, 0, 0);
    }

#pragma unroll
    for (int mf = 0; mf < 4; mf++)
#pragma unroll
        for (int reg = 0; reg < 4; reg++) {
            int row = mf * 16 + l4 * 4 + reg;
            int de = dstl[w][row];
            float* ob = out + (size_t)de * 160 + l16;
#pragma unroll
            for (int nf = 0; nf < 4; nf++)
                atomicAdd(ob + nf * 16, acc[mf][nf][reg]);
        }
}

// ---------------------------------------------------------------------------
// msg1o, T-scheme. Per wave 64 edges; g-frags processed in pairs.
__global__ __launch_bounds__(256, 3) void msg1o_kernel(
    const float* __restrict__ feat0e,
    const float* __restrict__ feat1o,
    const float* __restrict__ pos,
    const int* __restrict__ eidx,
    const int* __restrict__ i64flag,
    const char* __restrict__ wsp,
    float* __restrict__ out)
{
    __shared__ unsigned short vt[4][6144];   // [d*3+x][64 e] f16
    __shared__ float rell[4][64][3];
    __shared__ int srcl[4][64];
    __shared__ int dstl[4][64];

    const int tid = threadIdx.x, w = tid >> 6, lane = tid & 63;
    const int l4 = lane >> 4, l16 = lane & 15;
    const int e0 = blockIdx.x * 256 + w * 64;

    { // stage idx/rel + v tile [comp][e]
        int e = e0 + lane; int s_, d_;
        if (*i64flag) { s_ = (int)((const long long*)eidx)[e]; d_ = (int)((const long long*)eidx)[EE + e]; }
        else          { s_ = eidx[e];                          d_ = eidx[EE + e]; }
        srcl[w][lane] = s_; dstl[w][lane] = d_;
        rell[w][lane][0] = pos[d_ * 3 + 0] - pos[s_ * 3 + 0];
        rell[w][lane][1] = pos[d_ * 3 + 1] - pos[s_ * 3 + 1];
        rell[w][lane][2] = pos[d_ * 3 + 2] - pos[s_ * 3 + 2];
        const float* vp = feat1o + (size_t)s_ * 96;
#pragma unroll
        for (int q = 0; q < 24; q++) {
            float4 f = *(const float4*)(vp + q * 4);
            vt[w][(q * 4 + 0) * 64 + lane] = h2u((_Float16)f.x);
            vt[w][(q * 4 + 1) * 64 + lane] = h2u((_Float16)f.y);
            vt[w][(q * 4 + 2) * 64 + lane] = h2u((_Float16)f.z);
            vt[w][(q * 4 + 3) * 64 + lane] = h2u((_Float16)f.w);
        }
    }
    __syncthreads();

    const _Float16* es_g = (const _Float16*)(wsp + OFF_ES);
    const half8* wvs2p = (const half8*)(wsp + OFF_WVS2);
    const half8* wsvp  = (const half8*)(wsp + OFF_WSV);
    const half8* wxp   = (const half8*)(wsp + OFF_WX);

#pragma unroll 1
    for (int gp = 0; gp < 2; ++gp) {
        half8 esf[2][2];
#pragma unroll
        for (int gl = 0; gl < 2; gl++)
#pragma unroll
            for (int kf = 0; kf < 2; kf++)
                esf[gl][kf] = *(const half8*)(es_g +
                    (size_t)(e0 + (gp * 2 + gl) * 16 + l16) * 64 + kf * 32 + l4 * 8);

        f32x4 acc1[2][3][2];
#pragma unroll
        for (int gl = 0; gl < 2; gl++)
#pragma unroll
            for (int x = 0; x < 3; x++)
#pragma unroll
                for (int ch = 0; ch < 2; ch++) acc1[gl][x][ch] = (f32x4){0.f,0.f,0.f,0.f};

        // ---- T main loop: T[e, d, c] = es @ wvs2, consume with v ----
#pragma unroll 2
        for (int ck = 0; ck < 16; ++ck) {      // 2 d per chunk
            half8 bf[2][4];
#pragma unroll
            for (int kf = 0; kf < 2; kf++)
#pragma unroll
                for (int nfl = 0; nfl < 4; nfl++)
                    bf[kf][nfl] = wvs2p[(ck * 8 + kf * 4 + nfl) * 64 + lane];
#pragma unroll
            for (int gl = 0; gl < 2; gl++) {
                f32x4 tacc[4];
#pragma unroll
                for (int nfl = 0; nfl < 4; nfl++) tacc[nfl] = (f32x4){0.f,0.f,0.f,0.f};
#pragma unroll
                for (int kf = 0; kf < 2; kf++)
#pragma unroll
                    for (int nfl = 0; nfl < 4; nfl++)
                        tacc[nfl] = __builtin_amdgcn_mfma_f32_16x16x32_f16(
                            esf[gl][kf], bf[kf][nfl], tacc[nfl], 0, 0, 0);
#pragma unroll
                for (int dl = 0; dl < 2; dl++) {
                    int d = ck * 2 + dl;
#pragma unroll
                    for (int x = 0; x < 3; x++) {
                        half4 hv = *(const half4*)&vt[w][(d * 3 + x) * 64 +
                                                         (gp * 2 + gl) * 16 + l4 * 4];
                        f32x4 vf = __builtin_convertvector(hv, f32x4);
                        acc1[gl][x][0] += vf * tacc[dl * 2 + 0];
                        acc1[gl][x][1] += vf * tacc[dl * 2 + 1];
                    }
                }
            }
        }

        // ---- sv path: A[(e,x)][p] = s[e,p]*rel[e,x] ----
        {
            half8 bsv[2][2];
#pragma unroll
            for (int kf = 0; kf < 2; kf++)
#pragma unroll
                for (int nf = 0; nf < 2; nf++)
                    bsv[kf][nf] = wsvp[(size_t)(kf * 2 + nf) * 64 + lane];
#pragma unroll
            for (int gl = 0; gl < 2; gl++) {
                int erow = (gp * 2 + gl) * 16 + l16;
                const float* sp = feat0e + (size_t)srcl[w][erow] * 64 + l4 * 8;
                half8 sf[2];
#pragma unroll
                for (int kf = 0; kf < 2; kf++) {
                    float4 a = *(const float4*)(sp + kf * 32);
                    float4 b = *(const float4*)(sp + kf * 32 + 4);
                    half8 h;
                    h[0]=(_Float16)a.x; h[1]=(_Float16)a.y; h[2]=(_Float16)a.z; h[3]=(_Float16)a.w;
                    h[4]=(_Float16)b.x; h[5]=(_Float16)b.y; h[6]=(_Float16)b.z; h[7]=(_Float16)b.w;
                    sf[kf] = h;
                }
#pragma unroll
                for (int x = 0; x < 3; x++) {
                    _Float16 rl = (_Float16)rell[w][erow][x];
#pragma unroll
                    for (int kf = 0; kf < 2; kf++) {
                        half8 a = sf[kf] * rl;
#pragma unroll
                        for (int nf = 0; nf < 2; nf++)
                            acc1[gl][x][nf] = __builtin_amdgcn_mfma_f32_16x16x32_f16(
                                a, bsv[kf][nf], acc1[gl][x][nf], 0, 0, 0);
                    }
                }
            }
        }

        // ---- cross path: CX[x'] = v[:,:,x'] @ wx, combine with rel ----
        {
            half8 bx[2];
            bx[0] = wxp[lane];
            bx[1] = wxp[64 + lane];
#pragma unroll
            for (int gl = 0; gl < 2; gl++) {
                int g = gp * 2 + gl;
                f32x4 cx[3][2];
#pragma unroll
                for (int xp = 0; xp < 3; xp++) {
                    half8 av;
#pragma unroll
                    for (int j = 0; j < 8; j++)
                        av[j] = u2h(vt[w][((l4 * 8 + j) * 3 + xp) * 64 + g * 16 + l16]);
#pragma unroll
                    for (int nf = 0; nf < 2; nf++)
                        cx[xp][nf] = __builtin_amdgcn_mfma_f32_16x16x32_f16(
                            av, bx[nf], (f32x4){0.f,0.f,0.f,0.f}, 0, 0, 0);
                }
                f32x4 r[3];
#pragma unroll
                for (int x = 0; x < 3; x++)
#pragma unroll
                    for (int reg = 0; reg < 4; reg++)
                        r[x][reg] = rell[w][g * 16 + l4 * 4 + reg][x];
#pragma unroll
                for (int x = 0; x < 3; x++) {
                    const int x1 = (x + 1) % 3, x2 = (x + 2) % 3;
#pragma unroll
                    for (int ch = 0; ch < 2; ch++)
                        acc1[gl][x][ch] += r[x2] * cx[x1][ch] - r[x1] * cx[x2][ch];
                }
            }
        }

        // ---- scatter ----
#pragma unroll
        for (int gl = 0; gl < 2; gl++) {
            int g = gp * 2 + gl;
#pragma unroll
            for (int reg = 0; reg < 4; reg++) {
                int erow = g * 16 + l4 * 4 + reg;
                int de = dstl[w][erow];
                float* ob = out + (size_t)de * 160 + 64;
#pragma unroll
                for (int x = 0; x < 3; x++)
#pragma unroll
                    for (int ch = 0; ch < 2; ch++)
                        atomicAdd(ob + (ch * 16 + l16) * 3 + x, acc1[gl][x][ch][reg]);
            }
        }
    }
}

// ---------------------------------------------------------------------------
__global__ __launch_bounds__(256) void node_kernel(
    const float* __restrict__ feat0e,
    const float* __restrict__ feat1o,
    const float* __restrict__ Wg, const float* __restrict__ bg,
    const float* __restrict__ counts,
    float* __restrict__ out)
{
    const int w = threadIdx.x >> 6;
    const int n = blockIdx.x * 4 + w;
    const int lane = threadIdx.x & 63;
    __shared__ float a_lds[4][D0];
    __shared__ float gate_lds[4][D1];

    const float inv = 1.0f / fmaxf(counts[n], 1.0f);
    float a = out[(size_t)n * 160 + lane] * inv;
    a_lds[w][lane] = a;
    __syncthreads();

    out[(size_t)n * 160 + lane] = silu_f(a) + feat0e[(size_t)n * D0 + lane];

    if (lane < D1) {
        float gs = bg[lane];
        for (int p = 0; p < D0; ++p) gs = fmaf(a_lds[w][p], Wg[p * D1 + lane], gs);
        gate_lds[w][lane] = silu_f(gs);
    }
    __syncthreads();

    for (int idx = lane; idx < D1 * 3; idx += 64) {
        int c = idx / 3;
        size_t o = (size_t)n * 160 + 64 + idx;
        out[o] = fmaf(out[o] * inv, gate_lds[w][c], feat1o[(size_t)n * (D1 * 3) + idx]);
    }
}

// ---------------------------------------------------------------------------
// Fallback (round-1 monolithic VALU kernel) for small ws_size.
__global__ __launch_bounds__(256) void edge_kernel_fb(
    const float* __restrict__ feat0e, const float* __restrict__ feat1o,
    const float* __restrict__ edge_attr, const float* __restrict__ pos,
    const int* __restrict__ eidx,
    const float* __restrict__ W1, const float* __restrict__ b1,
    const float* __restrict__ W2, const float* __restrict__ b2,
    const float* __restrict__ W3, const float* __restrict__ b3,
    const float* __restrict__ wss, const float* __restrict__ wvv,
    const float* __restrict__ wsv, const float* __restrict__ wvs,
    const float* __restrict__ wcross,
    const int* __restrict__ i64flag,
    float* __restrict__ out, float* __restrict__ counts)
{
    const int e = blockIdx.x * 256 + threadIdx.x;
    int src, dst;
    if (*i64flag) { src = (int)((const long long*)eidx)[e]; dst = (int)((const long long*)eidx)[EE + e]; }
    else          { src = eidx[e];                          dst = eidx[EE + e]; }
    const float rel0 = pos[dst * 3 + 0] - pos[src * 3 + 0];
    const float rel1 = pos[dst * 3 + 1] - pos[src * 3 + 1];
    const float rel2 = pos[dst * 3 + 2] - pos[src * 3 + 2];
    float h1[HH];
#pragma unroll
    for (int j = 0; j < HH; ++j) h1[j] = b1[j];
    for (int i = 0; i < HH; ++i) {
        float a = edge_attr[(size_t)e * HH + i];
        const float* ww = W1 + i * HH;
#pragma unroll
        for (int j = 0; j < HH; ++j) h1[j] = fmaf(a, ww[j], h1[j]);
    }
#pragma unroll
    for (int j = 0; j < HH; ++j) h1[j] = silu_f(h1[j]);
    float h2[HH];
#pragma unroll
    for (int j = 0; j < HH; ++j) h2[j] = b2[j];
#pragma unroll
    for (int i = 0; i < HH; ++i) {
        float a = h1[i];
        const float* ww = W2 + i * HH;
#pragma unroll
        for (int j = 0; j < HH; ++j) h2[j] = fmaf(a, ww[j], h2[j]);
    }
#pragma unroll
    for (int j = 0; j < HH; ++j) h2[j] = silu_f(h2[j]);
    float es[HH];
#pragma unroll
    for (int j = 0; j < HH; ++j) es[j] = b3[j];
#pragma unroll
    for (int i = 0; i < HH; ++i) {
        float a = h2[i];
        const float* ww = W3 + i * HH;
#pragma unroll
        for (int j = 0; j < HH; ++j) es[j] = fmaf(a, ww[j], es[j]);
    }
    float dotv[D1];
#pragma unroll
    for (int d = 0; d < D1; ++d) {
        float v0 = feat1o[(size_t)src * 96 + d * 3 + 0];
        float v1 = feat1o[(size_t)src * 96 + d * 3 + 1];
        float v2 = feat1o[(size_t)src * 96 + d * 3 + 2];
        dotv[d] = fmaf(v0, rel0, fmaf(v1, rel1, v2 * rel2));
    }
#pragma unroll
    for (int ob = 0; ob < 4; ++ob) {
        const int o0 = ob * 16;
        float acc[16];
#pragma unroll
        for (int j = 0; j < 16; ++j) acc[j] = 0.f;
#pragma unroll
        for (int d = 0; d < D1; ++d) {
            const float* ww = wvv + d * D0 + o0;
#pragma unroll
            for (int j = 0; j < 16; ++j) acc[j] = fmaf(dotv[d], ww[j], acc[j]);
        }
        for (int p = 0; p < D0; ++p) {
            float sval = feat0e[(size_t)src * D0 + p];
            const float* wp = wss + (size_t)p * HH * D0 + o0;
#pragma unroll
            for (int h = 0; h < HH; ++h) {
                float c = sval * es[h];
                const float* ww = wp + h * D0;
#pragma unroll
                for (int j = 0; j < 16; ++j) acc[j] = fmaf(c, ww[j], acc[j]);
            }
        }
        float* obase = out + (size_t)dst * 160 + o0;
#pragma unroll
        for (int j = 0; j < 16; ++j) atomicAdd(obase + j, acc[j]);
    }
    atomicAdd(counts + dst, 1.0f);
    float g[D1];
#pragma unroll
    for (int c = 0; c < D1; ++c) g[c] = 0.f;
    for (int p = 0; p < D0; ++p) {
        float sval = feat0e[(size_t)src * D0 + p];
        const float* ww = wsv + p * D1;
#pragma unroll
        for (int c = 0; c < D1; ++c) g[c] = fmaf(sval, ww[c], g[c]);
    }
    float acc1[D1 * 3];
#pragma unroll
    for (int c = 0; c < D1; ++c) {
        acc1[c * 3 + 0] = g[c] * rel0;
        acc1[c * 3 + 1] = g[c] * rel1;
        acc1[c * 3 + 2] = g[c] * rel2;
    }
    for (int d = 0; d < D1; ++d) {
        float v0 = feat1o[(size_t)src * 96 + d * 3 + 0];
        float v1 = feat1o[(size_t)src * 96 + d * 3 + 1];
        float v2 = feat1o[(size_t)src * 96 + d * 3 + 2];
        float cx0 = fmaf(v1, rel2, -v2 * rel1);
        float cx1 = fmaf(v2, rel0, -v0 * rel2);
        float cx2 = fmaf(v0, rel1, -v1 * rel0);
        const float* wd = wvs + (size_t)d * HH * D1;
        const float* wc = wcross + d * D1;
#pragma unroll
        for (int cb = 0; cb < 2; ++cb) {
            float t[16];
#pragma unroll
            for (int cc = 0; cc < 16; ++cc) t[cc] = 0.f;
#pragma unroll
            for (int h = 0; h < HH; ++h) {
                const float* ww = wd + h * D1 + cb * 16;
                float ev = es[h];
#pragma unroll
                for (int cc = 0; cc < 16; ++cc) t[cc] = fmaf(ev, ww[cc], t[cc]);
            }
#pragma unroll
            for (int cc = 0; cc < 16; ++cc) {
                int c = cb * 16 + cc;
                float tc = t[cc], wcc = wc[c];
                acc1[c * 3 + 0] = fmaf(v0, tc, fmaf(cx0, wcc, acc1[c * 3 + 0]));
                acc1[c * 3 + 1] = fmaf(v1, tc, fmaf(cx1, wcc, acc1[c * 3 + 1]));
                acc1[c * 3 + 2] = fmaf(v2, tc, fmaf(cx2, wcc, acc1[c * 3 + 2]));
            }
        }
    }
    float* obase1 = out + (size_t)dst * 160 + 64;
#pragma unroll
    for (int k = 0; k < D1 * 3; ++k) atomicAdd(obase1 + k, acc1[k]);
}

// ---------------------------------------------------------------------------
extern "C" void kernel_launch(void* const* d_in, const int* in_sizes, int n_in,
                              void* d_out, int out_size, void* d_ws, size_t ws_size,
                              hipStream_t stream) {
    const float* feat0e    = (const float*)d_in[0];
    const float* feat1o    = (const float*)d_in[1];
    const float* edge_attr = (const float*)d_in[2];
    const float* pos       = (const float*)d_in[3];
    const int*   eidx      = (const int*)d_in[4];
    const float* W1 = (const float*)d_in[5];
    const float* b1 = (const float*)d_in[6];
    const float* W2 = (const float*)d_in[7];
    const float* b2 = (const float*)d_in[8];
    const float* W3 = (const float*)d_in[9];
    const float* b3 = (const float*)d_in[10];
    const float* wss    = (const float*)d_in[11];
    const float* wvv    = (const float*)d_in[12];
    const float* wsv    = (const float*)d_in[13];
    const float* wvs    = (const float*)d_in[14];
    const float* wcross = (const float*)d_in[15];
    const float* Wg = (const float*)d_in[16];
    const float* bg = (const float*)d_in[17];

    float* out    = (float*)d_out;
    char*  ws     = (char*)d_ws;
    float* counts = (float*)(ws + OFF_CNT);
    int*   flag   = (int*)(ws + OFF_FLAG);

    hipMemsetAsync(d_out, 0, (size_t)out_size * sizeof(float), stream);
    hipMemsetAsync(d_ws, 0, 80064, stream);

    detect_idx_kernel<<<1, 1, 0, stream>>>(eidx, flag);

    if (ws_size >= WS_NEED) {
        _Float16* es_g = (_Float16*)(ws + OFF_ES);
        prep_kernel<<<169, 256, 0, stream>>>(wss, wvv, wsv, wvs, wcross, W1, W2, W3, ws);
        mlp_kernel<<<EE / 256, 256, 0, stream>>>(edge_attr, b1, b2, b3,
                                                 (const char*)ws, es_g);
        msg0e_kernel<<<EE / 256, 256, 0, stream>>>(feat0e, feat1o, pos, eidx, flag,
                                                   (const char*)ws, out, counts);
        msg1o_kernel<<<EE / 256, 256, 0, stream>>>(feat0e, feat1o, pos, eidx, flag,
                                                   (const char*)ws, out);
    } else {
        edge_kernel_fb<<<EE / 256, 256, 0, stream>>>(
            feat0e, feat1o, edge_attr, pos, eidx,
            W1, b1, W2, b2, W3, b3, wss, wvv, wsv, wvs, wcross,
            flag, out, counts);
    }
    node_kernel<<<NN / 4, 256, 0, stream>>>(feat0e, feat1o, Wg, bg, counts, out);
}

// Round 4
// 767.575 us; speedup vs baseline: 32.3628x; 1.4261x over previous
//
#include <hip/hip_runtime.h>

// EquivariantConvLayer — Round 4: atomic-free pipeline.
// Counting-sort edges by dst -> msg kernels (fused MFMA MLP) write per-edge
// messages linearly in f16 -> gather kernels sum contiguous ranges per node.
// msg buffer reused: msg0 (82MB) -> gather0 -> msg1 (123MB) -> gather1.

#define NN 20000
#define EE 640000
#define D0 64
#define D1 32
#define HH 64

typedef _Float16 half8 __attribute__((ext_vector_type(8)));
typedef _Float16 half4 __attribute__((ext_vector_type(4)));
typedef float f32x4 __attribute__((ext_vector_type(4)));

__device__ __forceinline__ float silu_f(float x) { return x / (1.0f + __expf(-x)); }
__device__ __forceinline__ _Float16 u2h(unsigned short u) {
    union { unsigned short u; _Float16 h; } c; c.u = u; return c.h;
}
__device__ __forceinline__ unsigned short h2u(_Float16 h) {
    union { unsigned short u; _Float16 h; } c; c.h = h; return c.u;
}
__device__ __forceinline__ half8 pack8(float4 a, float4 b) {
    half8 h;
    h[0]=(_Float16)a.x; h[1]=(_Float16)a.y; h[2]=(_Float16)a.z; h[3]=(_Float16)a.w;
    h[4]=(_Float16)b.x; h[5]=(_Float16)b.y; h[6]=(_Float16)b.z; h[7]=(_Float16)b.w;
    return h;
}

// ---- workspace layout (bytes) ----
#define OFF_HIST  0ull           // NN*4 (fallback: float counts)
#define OFF_RS    81920ull       // (NN+1)*4 row_start
#define OFF_CUR   163840ull      // NN*4 cursors
#define OFF_FLAG  245760ull      // 4
#define OFF_SRCA  262144ull      // E*4 sorted src
#define OFF_DSTA  2822144ull     // E*4 sorted dst
#define OFF_PE    5382144ull     // E*4 sorted original edge id
#define OFF_WSS   7942144ull     // 512KB
#define OFF_WVS2  8466432ull     // 128KB
#define OFF_WVV   8597504ull     // 4KB
#define OFF_WSV   8601600ull     // 4KB
#define OFF_WX    8605696ull     // 2KB
#define OFF_WMLP  8607744ull     // 24KB
#define OFF_MSG   8632320ull     // E*96*2 = 122880000 (msg0 uses first E*64*2)
#define WS_NEED   (8632320ull + 122880000ull)

// ---------------------------------------------------------------------------
__global__ void detect_idx_kernel(const int* __restrict__ eidx, int* __restrict__ flag) {
    int odd_nz = 0, even_nz = 0;
    for (int k = 0; k < 64; ++k) {
        if (eidx[2 * k + 1] != 0) odd_nz = 1;
        if (eidx[2 * k] != 0) even_nz = 1;
    }
    *flag = (!odd_nz && even_nz) ? 1 : 0;  // 1 => int64
}

__global__ __launch_bounds__(256) void hist_kernel(
    const int* __restrict__ eidx, const int* __restrict__ flag,
    int* __restrict__ hist)
{
    const int e = blockIdx.x * 256 + threadIdx.x;
    int d_;
    if (*flag) d_ = (int)((const long long*)eidx)[EE + e];
    else       d_ = eidx[EE + e];
    atomicAdd(hist + d_, 1);
}

__global__ __launch_bounds__(1024) void scan_kernel(
    const int* __restrict__ hist, int* __restrict__ rs, int* __restrict__ cur)
{
    __shared__ int part[1024];
    const int t = threadIdx.x;
    const int base = t * 20;
    int loc[20];
    int tot = 0;
#pragma unroll
    for (int k = 0; k < 20; ++k) {
        int n = base + k;
        int h = (n < NN) ? hist[n] : 0;
        loc[k] = tot; tot += h;
    }
    part[t] = tot;
    __syncthreads();
    for (int off = 1; off < 1024; off <<= 1) {
        int v = (t >= off) ? part[t - off] : 0;
        __syncthreads();
        part[t] += v;
        __syncthreads();
    }
    int excl = part[t] - tot;
#pragma unroll
    for (int k = 0; k < 20; ++k) {
        int n = base + k;
        if (n < NN) { rs[n] = excl + loc[k]; cur[n] = excl + loc[k]; }
    }
    if (t == 1023) rs[NN] = part[1023];
}

__global__ __launch_bounds__(256) void scatter_kernel(
    const int* __restrict__ eidx, const int* __restrict__ flag,
    int* __restrict__ cur, int* __restrict__ srca, int* __restrict__ dsta,
    int* __restrict__ pe)
{
    const int e = blockIdx.x * 256 + threadIdx.x;
    int s_, d_;
    if (*flag) { s_ = (int)((const long long*)eidx)[e]; d_ = (int)((const long long*)eidx)[EE + e]; }
    else       { s_ = eidx[e];                          d_ = eidx[EE + e]; }
    int pos = atomicAdd(cur + d_, 1);
    srca[pos] = s_; dsta[pos] = d_; pe[pos] = e;
}

// ---------------------------------------------------------------------------
// Permute weights into MFMA B-fragment-linear f16 layouts (as round 3).
__global__ __launch_bounds__(256) void prep_kernel(
    const float* __restrict__ wss, const float* __restrict__ wvv,
    const float* __restrict__ wsv, const float* __restrict__ wvs,
    const float* __restrict__ wx,
    const float* __restrict__ W1, const float* __restrict__ W2,
    const float* __restrict__ W3, char* __restrict__ ws)
{
    int id = blockIdx.x * 256 + threadIdx.x;
    if (id >= 43136) return;
    int l = id & 63;
    int l4 = l >> 4, l16 = l & 15;
    half8 o;
    _Float16* dst;
    if (id < 32768) {                       // wss: p(64) x frag(8 = kf*4+nf)
        int p = id >> 9; int frag = (id >> 6) & 7;
        int kf = frag >> 2, nf = frag & 3;
#pragma unroll
        for (int j = 0; j < 8; j++) {
            int h = kf * 32 + l4 * 8 + j, oo = nf * 16 + l16;
            o[j] = (_Float16)wss[((size_t)p * 64 + h) * 64 + oo];
        }
        dst = (_Float16*)(ws + OFF_WSS) + (size_t)id * 8;
    } else if (id < 40960) {                // wvs2: B[h][col=d*32+c]
        int i = id - 32768;
        int f = i >> 6;
        int chunk = f >> 3, kf = (f >> 2) & 1, nfl = f & 3;
#pragma unroll
        for (int j = 0; j < 8; j++) {
            int h = kf * 32 + l4 * 8 + j;
            int col = chunk * 64 + nfl * 16 + l16;
            int d = col >> 5, c = col & 31;
            o[j] = (_Float16)wvs[((size_t)d * 64 + h) * 32 + c];
        }
        dst = (_Float16*)(ws + OFF_WVS2) + (size_t)i * 8;
    } else if (id < 41216) {                // wvv
        int i = id - 40960; int nf = i >> 6;
#pragma unroll
        for (int j = 0; j < 8; j++) {
            int d = l4 * 8 + j, oo = nf * 16 + l16;
            o[j] = (_Float16)wvv[d * 64 + oo];
        }
        dst = (_Float16*)(ws + OFF_WVV) + (size_t)i * 8;
    } else if (id < 41472) {                // wsv
        int i = id - 41216; int frag = i >> 6;
        int kf = frag >> 1, nf = frag & 1;
#pragma unroll
        for (int j = 0; j < 8; j++) {
            int p = kf * 32 + l4 * 8 + j, c = nf * 16 + l16;
            o[j] = (_Float16)wsv[p * 32 + c];
        }
        dst = (_Float16*)(ws + OFF_WSV) + (size_t)i * 8;
    } else if (id < 41600) {                // wcross
        int i = id - 41472; int nf = i >> 6;
#pragma unroll
        for (int j = 0; j < 8; j++) {
            int d = l4 * 8 + j, c = nf * 16 + l16;
            o[j] = (_Float16)wx[d * 32 + c];
        }
        dst = (_Float16*)(ws + OFF_WX) + (size_t)i * 8;
    } else {                                // W1..W3
        int i = id - 41600; int f = i >> 6;
        int layer = f >> 3, kf = (f >> 2) & 1, nf = f & 3;
        const float* W = layer == 0 ? W1 : (layer == 1 ? W2 : W3);
#pragma unroll
        for (int j = 0; j < 8; j++) {
            int r = kf * 32 + l4 * 8 + j, cc = nf * 16 + l16;
            o[j] = (_Float16)W[r * 64 + cc];
        }
        dst = (_Float16*)(ws + OFF_WMLP) + (size_t)i * 8;
    }
    *(half8*)dst = o;
}

// ---------------------------------------------------------------------------
// Fused MLP (per wave, exchange buffer xch = 64x64 f16 in LDS, in-place).
// Produces es A-frags in esf[4][2].
__device__ __forceinline__ void mlp_wave(
    const float* __restrict__ edge_attr,
    const float* __restrict__ b1, const float* __restrict__ b2,
    const float* __restrict__ b3,
    const char* __restrict__ wsp,
    const int* __restrict__ pel_w,      // 64 sorted-edge -> original edge ids
    unsigned short* __restrict__ xch,   // 4096 entries
    int lane, half8 esf[4][2])
{
    const int l4 = lane >> 4, l16 = lane & 15;
    const half8* wm = (const half8*)(wsp + OFF_WMLP);

    float bias[3][4];
#pragma unroll
    for (int nf = 0; nf < 4; nf++) {
        bias[0][nf] = b1[nf * 16 + l16];
        bias[1][nf] = b2[nf * 16 + l16];
        bias[2][nf] = b3[nf * 16 + l16];
    }

    half8 af[4][2];
#pragma unroll
    for (int mf = 0; mf < 4; mf++) {
        int e = pel_w[mf * 16 + l16];
        const float* p = edge_attr + (size_t)e * 64 + l4 * 8;
#pragma unroll
        for (int kf = 0; kf < 2; kf++)
            af[mf][kf] = pack8(*(const float4*)(p + kf * 32),
                               *(const float4*)(p + kf * 32 + 4));
    }

#pragma unroll
    for (int layer = 0; layer < 3; ++layer) {
        f32x4 acc[4][4];
#pragma unroll
        for (int mf = 0; mf < 4; mf++)
#pragma unroll
            for (int nf = 0; nf < 4; nf++) acc[mf][nf] = (f32x4){0.f,0.f,0.f,0.f};
#pragma unroll
        for (int kf = 0; kf < 2; kf++)
#pragma unroll
            for (int mf = 0; mf < 4; mf++)
#pragma unroll
                for (int nf = 0; nf < 4; nf++)
                    acc[mf][nf] = __builtin_amdgcn_mfma_f32_16x16x32_f16(
                        af[mf][kf], wm[(layer * 8 + kf * 4 + nf) * 64 + lane],
                        acc[mf][nf], 0, 0, 0);
#pragma unroll
        for (int mf = 0; mf < 4; mf++)
#pragma unroll
            for (int nf = 0; nf < 4; nf++)
#pragma unroll
                for (int reg = 0; reg < 4; reg++) {
                    int row = mf * 16 + l4 * 4 + reg;
                    int col = nf * 16 + l16;
                    float v = acc[mf][nf][reg] + bias[layer][nf];
                    if (layer < 2) v = silu_f(v);
                    xch[row * 64 + (col ^ ((row & 7) << 3))] = h2u((_Float16)v);
                }
        if (layer < 2) {
#pragma unroll
            for (int mf = 0; mf < 4; mf++)
#pragma unroll
                for (int kf = 0; kf < 2; kf++) {
                    int row = mf * 16 + l16;
                    int cs = kf * 32 + l4 * 8;
                    af[mf][kf] = *(const half8*)&xch[row * 64 + (cs ^ ((row & 7) << 3))];
                }
        }
    }
    // final layer output -> es A-frags
#pragma unroll
    for (int mf = 0; mf < 4; mf++)
#pragma unroll
        for (int kf = 0; kf < 2; kf++) {
            int row = mf * 16 + l16;
            int cs = kf * 32 + l4 * 8;
            esf[mf][kf] = *(const half8*)&xch[row * 64 + (cs ^ ((row & 7) << 3))];
        }
}

// ---------------------------------------------------------------------------
// msg0e: fused MLP + ss-einsum (LDS-staged wss chunks) + dotv; linear f16 store.
__global__ __launch_bounds__(256, 2) void msg0e_kernel(
    const float* __restrict__ feat0e,
    const float* __restrict__ feat1o,
    const float* __restrict__ edge_attr,
    const float* __restrict__ pos,
    const float* __restrict__ b1, const float* __restrict__ b2,
    const float* __restrict__ b3,
    const char* __restrict__ wsp,
    _Float16* __restrict__ msg0)
{
    __shared__ unsigned short st[4][4096];   // per-wave: mlp exchange, then s-tile, then C-store
    __shared__ unsigned short wf[16384];     // block-shared wss chunk (4 p's, 32KB)
    __shared__ float rell[4][64][3];
    __shared__ int   srcl[4][64];
    __shared__ int   pel[4][64];

    const int tid = threadIdx.x, w = tid >> 6, lane = tid & 63;
    const int l4 = lane >> 4, l16 = lane & 15;
    const long i0 = (long)blockIdx.x * 256 + w * 64;

    {
        long p = i0 + lane;
        int s_ = ((const int*)(wsp + OFF_SRCA))[p];
        int d_ = ((const int*)(wsp + OFF_DSTA))[p];
        pel[w][lane] = ((const int*)(wsp + OFF_PE))[p];
        srcl[w][lane] = s_;
        rell[w][lane][0] = pos[d_ * 3 + 0] - pos[s_ * 3 + 0];
        rell[w][lane][1] = pos[d_ * 3 + 1] - pos[s_ * 3 + 1];
        rell[w][lane][2] = pos[d_ * 3 + 2] - pos[s_ * 3 + 2];
    }
    __syncthreads();

    half8 esf[4][2];
    mlp_wave(edge_attr, b1, b2, b3, wsp, pel[w], st[w], lane, esf);
    __syncthreads();

    // stage s-tile (gather by src), f32 -> f16, swizzled
#pragma unroll
    for (int r4 = 0; r4 < 4; r4++) {
        int row = r4 * 16 + (lane >> 2);
        int ch = lane & 3;
        const float* sp = feat0e + (size_t)srcl[w][row] * 64 + ch * 16;
        half8 h0 = pack8(*(const float4*)(sp + 0), *(const float4*)(sp + 4));
        half8 h1 = pack8(*(const float4*)(sp + 8), *(const float4*)(sp + 12));
        int r7 = row & 7;
        *(half8*)&st[w][row * 64 + (((ch * 2) ^ r7) * 8)]     = h0;
        *(half8*)&st[w][row * 64 + (((ch * 2 + 1) ^ r7) * 8)] = h1;
    }
    __syncthreads();

    f32x4 acc[4][4];
#pragma unroll
    for (int mf = 0; mf < 4; mf++)
#pragma unroll
        for (int nf = 0; nf < 4; nf++) acc[mf][nf] = (f32x4){0.f, 0.f, 0.f, 0.f};

    const half8* wss_g = (const half8*)(wsp + OFF_WSS);
    half8* wfh = (half8*)wf;
    for (int pc = 0; pc < 16; ++pc) {
        __syncthreads();
#pragma unroll
        for (int q = 0; q < 8; q++)
            wfh[q * 256 + tid] = wss_g[pc * 2048 + q * 256 + tid];
        __syncthreads();
#pragma unroll
        for (int pl = 0; pl < 4; ++pl) {
            const int p = pc * 4 + pl;
            _Float16 sv[4];
#pragma unroll
            for (int mf = 0; mf < 4; mf++) {
                int row = mf * 16 + l16;
                sv[mf] = u2h(st[w][row * 64 + (((p >> 3) ^ (row & 7)) * 8) + (p & 7)]);
            }
#pragma unroll
            for (int kf = 0; kf < 2; kf++) {
                half8 bf[4];
#pragma unroll
                for (int nf = 0; nf < 4; nf++)
                    bf[nf] = wfh[(pl * 8 + kf * 4 + nf) * 64 + lane];
#pragma unroll
                for (int mf = 0; mf < 4; mf++) {
                    half8 a = esf[mf][kf] * sv[mf];
#pragma unroll
                    for (int nf = 0; nf < 4; nf++)
                        acc[mf][nf] = __builtin_amdgcn_mfma_f32_16x16x32_f16(a, bf[nf], acc[mf][nf], 0, 0, 0);
                }
            }
        }
    }

    // dotv chunk
    half8 dvf[4];
#pragma unroll
    for (int mf = 0; mf < 4; mf++) {
        int row = mf * 16 + l16;
        int se = srcl[w][row];
        float r0 = rell[w][row][0], r1 = rell[w][row][1], r2 = rell[w][row][2];
        const float* vp = feat1o + (size_t)se * 96 + l4 * 24;
        float4 A = *(const float4*)(vp + 0),  B = *(const float4*)(vp + 4);
        float4 C = *(const float4*)(vp + 8),  D = *(const float4*)(vp + 12);
        float4 E = *(const float4*)(vp + 16), F = *(const float4*)(vp + 20);
        dvf[mf][0] = (_Float16)(A.x * r0 + A.y * r1 + A.z * r2);
        dvf[mf][1] = (_Float16)(A.w * r0 + B.x * r1 + B.y * r2);
        dvf[mf][2] = (_Float16)(B.z * r0 + B.w * r1 + C.x * r2);
        dvf[mf][3] = (_Float16)(C.y * r0 + C.z * r1 + C.w * r2);
        dvf[mf][4] = (_Float16)(D.x * r0 + D.y * r1 + D.z * r2);
        dvf[mf][5] = (_Float16)(D.w * r0 + E.x * r1 + E.y * r2);
        dvf[mf][6] = (_Float16)(E.z * r0 + E.w * r1 + F.x * r2);
        dvf[mf][7] = (_Float16)(F.y * r0 + F.z * r1 + F.w * r2);
    }
    const half8* wvvp = (const half8*)(wsp + OFF_WVV);
#pragma unroll
    for (int nf = 0; nf < 4; nf++) {
        half8 bvv = wvvp[nf * 64 + lane];
#pragma unroll
        for (int mf = 0; mf < 4; mf++)
            acc[mf][nf] = __builtin_amdgcn_mfma_f32_16x16x32_f16(dvf[mf], bvv, acc[mf][nf], 0, 0, 0);
    }

    // store: C -> LDS (f16, swizzled) -> coalesced global
#pragma unroll
    for (int mf = 0; mf < 4; mf++)
#pragma unroll
        for (int nf = 0; nf < 4; nf++)
#pragma unroll
            for (int reg = 0; reg < 4; reg++) {
                int row = mf * 16 + l4 * 4 + reg;
                int col = nf * 16 + l16;
                st[w][row * 64 + (col ^ ((row & 7) << 3))] = h2u((_Float16)acc[mf][nf][reg]);
            }
#pragma unroll
    for (int t = 0; t < 8; t++) {
        int row = t * 8 + (lane >> 3);
        int c8 = lane & 7;
        half8 v = *(const half8*)&st[w][row * 64 + ((c8 * 8) ^ ((row & 7) << 3))];
        *(half8*)(msg0 + (size_t)(i0 + row) * 64 + c8 * 8) = v;
    }
}

// ---------------------------------------------------------------------------
// msg1o: fused MLP + T-scheme (all 4 g at once) + sv + cross; linear f16 store.
__global__ __launch_bounds__(256, 2) void msg1o_kernel(
    const float* __restrict__ feat0e,
    const float* __restrict__ feat1o,
    const float* __restrict__ edge_attr,
    const float* __restrict__ pos,
    const float* __restrict__ b1, const float* __restrict__ b2,
    const float* __restrict__ b3,
    const char* __restrict__ wsp,
    _Float16* __restrict__ msg1)
{
    __shared__ unsigned short vt[4][6144];   // per-wave: mlp exchange, then [d*3+x][e] v-tile, then C-store
    __shared__ float rell[4][64][3];
    __shared__ int srcl[4][64];
    __shared__ int pel[4][64];

    const int tid = threadIdx.x, w = tid >> 6, lane = tid & 63;
    const int l4 = lane >> 4, l16 = lane & 15;
    const long i0 = (long)blockIdx.x * 256 + w * 64;

    {
        long p = i0 + lane;
        int s_ = ((const int*)(wsp + OFF_SRCA))[p];
        int d_ = ((const int*)(wsp + OFF_DSTA))[p];
        pel[w][lane] = ((const int*)(wsp + OFF_PE))[p];
        srcl[w][lane] = s_;
        rell[w][lane][0] = pos[d_ * 3 + 0] - pos[s_ * 3 + 0];
        rell[w][lane][1] = pos[d_ * 3 + 1] - pos[s_ * 3 + 1];
        rell[w][lane][2] = pos[d_ * 3 + 2] - pos[s_ * 3 + 2];
    }
    __syncthreads();

    half8 esf[4][2];
    mlp_wave(edge_attr, b1, b2, b3, wsp, pel[w], vt[w], lane, esf);
    __syncthreads();

    { // stage v tile [comp][e] (overwrites mlp exchange)
        const float* vp = feat1o + (size_t)srcl[w][lane] * 96;
#pragma unroll
        for (int q = 0; q < 24; q++) {
            float4 f = *(const float4*)(vp + q * 4);
            vt[w][(q * 4 + 0) * 64 + lane] = h2u((_Float16)f.x);
            vt[w][(q * 4 + 1) * 64 + lane] = h2u((_Float16)f.y);
            vt[w][(q * 4 + 2) * 64 + lane] = h2u((_Float16)f.z);
            vt[w][(q * 4 + 3) * 64 + lane] = h2u((_Float16)f.w);
        }
    }
    __syncthreads();

    const half8* wvs2p = (const half8*)(wsp + OFF_WVS2);
    const half8* wsvp  = (const half8*)(wsp + OFF_WSV);
    const half8* wxp   = (const half8*)(wsp + OFF_WX);

    f32x4 acc1[4][3][2];
#pragma unroll
    for (int g = 0; g < 4; g++)
#pragma unroll
        for (int x = 0; x < 3; x++)
#pragma unroll
            for (int ch = 0; ch < 2; ch++) acc1[g][x][ch] = (f32x4){0.f,0.f,0.f,0.f};

    // ---- T main loop ----
#pragma unroll 2
    for (int ck = 0; ck < 16; ++ck) {
        half8 bf[2][4];
#pragma unroll
        for (int kf = 0; kf < 2; kf++)
#pragma unroll
            for (int nfl = 0; nfl < 4; nfl++)
                bf[kf][nfl] = wvs2p[(ck * 8 + kf * 4 + nfl) * 64 + lane];
#pragma unroll
        for (int g = 0; g < 4; g++) {
            f32x4 tacc[4];
#pragma unroll
            for (int nfl = 0; nfl < 4; nfl++) tacc[nfl] = (f32x4){0.f,0.f,0.f,0.f};
#pragma unroll
            for (int kf = 0; kf < 2; kf++)
#pragma unroll
                for (int nfl = 0; nfl < 4; nfl++)
                    tacc[nfl] = __builtin_amdgcn_mfma_f32_16x16x32_f16(
                        esf[g][kf], bf[kf][nfl], tacc[nfl], 0, 0, 0);
#pragma unroll
            for (int dl = 0; dl < 2; dl++) {
                int d = ck * 2 + dl;
#pragma unroll
                for (int x = 0; x < 3; x++) {
                    half4 hv = *(const half4*)&vt[w][(d * 3 + x) * 64 + g * 16 + l4 * 4];
                    f32x4 vf = __builtin_convertvector(hv, f32x4);
                    acc1[g][x][0] += vf * tacc[dl * 2 + 0];
                    acc1[g][x][1] += vf * tacc[dl * 2 + 1];
                }
            }
        }
    }

    // ---- sv path ----
    {
        half8 bsv[2][2];
#pragma unroll
        for (int kf = 0; kf < 2; kf++)
#pragma unroll
            for (int nf = 0; nf < 2; nf++)
                bsv[kf][nf] = wsvp[(size_t)(kf * 2 + nf) * 64 + lane];
#pragma unroll
        for (int g = 0; g < 4; g++) {
            int erow = g * 16 + l16;
            const float* sp = feat0e + (size_t)srcl[w][erow] * 64 + l4 * 8;
            half8 sf[2];
#pragma unroll
            for (int kf = 0; kf < 2; kf++)
                sf[kf] = pack8(*(const float4*)(sp + kf * 32),
                               *(const float4*)(sp + kf * 32 + 4));
#pragma unroll
            for (int x = 0; x < 3; x++) {
                _Float16 rl = (_Float16)rell[w][erow][x];
#pragma unroll
                for (int kf = 0; kf < 2; kf++) {
                    half8 a = sf[kf] * rl;
#pragma unroll
                    for (int nf = 0; nf < 2; nf++)
                        acc1[g][x][nf] = __builtin_amdgcn_mfma_f32_16x16x32_f16(
                            a, bsv[kf][nf], acc1[g][x][nf], 0, 0, 0);
                }
            }
        }
    }

    // ---- cross path ----
    {
        half8 bx[2];
        bx[0] = wxp[lane];
        bx[1] = wxp[64 + lane];
#pragma unroll
        for (int g = 0; g < 4; g++) {
            f32x4 cx[3][2];
#pragma unroll
            for (int xp = 0; xp < 3; xp++) {
                half8 av;
#pragma unroll
                for (int j = 0; j < 8; j++)
                    av[j] = u2h(vt[w][((l4 * 8 + j) * 3 + xp) * 64 + g * 16 + l16]);
#pragma unroll
                for (int nf = 0; nf < 2; nf++)
                    cx[xp][nf] = __builtin_amdgcn_mfma_f32_16x16x32_f16(
                        av, bx[nf], (f32x4){0.f,0.f,0.f,0.f}, 0, 0, 0);
            }
            f32x4 r[3];
#pragma unroll
            for (int x = 0; x < 3; x++)
#pragma unroll
                for (int reg = 0; reg < 4; reg++)
                    r[x][reg] = rell[w][g * 16 + l4 * 4 + reg][x];
#pragma unroll
            for (int x = 0; x < 3; x++) {
                const int x1 = (x + 1) % 3, x2 = (x + 2) % 3;
#pragma unroll
                for (int ch = 0; ch < 2; ch++)
                    acc1[g][x][ch] += r[x2] * cx[x1][ch] - r[x1] * cx[x2][ch];
            }
        }
    }

    // ---- store: C -> LDS (planar col' = x*32+c, f16, swizzled) -> global ----
    __syncthreads();   // everyone done reading vt
#pragma unroll
    for (int g = 0; g < 4; g++)
#pragma unroll
        for (int reg = 0; reg < 4; reg++) {
            int row = g * 16 + l4 * 4 + reg;
            int sw = (row & 3) << 3;
#pragma unroll
            for (int x = 0; x < 3; x++)
#pragma unroll
                for (int ch = 0; ch < 2; ch++) {
                    int c32 = ch * 16 + l16;
                    vt[w][row * 96 + x * 32 + (c32 ^ sw)] = h2u((_Float16)acc1[g][x][ch][reg]);
                }
        }
#pragma unroll
    for (int tt = 0; tt < 12; tt++) {
        int x = tt >> 2, rem = (tt & 3) * 8;
        int col = x * 32 + (rem ^ ((lane & 3) << 3));
        half8 v = *(const half8*)&vt[w][lane * 96 + col];
        *(half8*)(msg1 + (size_t)(i0 + lane) * 96 + tt * 8) = v;
    }
}

// ---------------------------------------------------------------------------
// gather0: per-node sum of msg0 range + out0e + gates (stashed in out1o slots).
__global__ __launch_bounds__(256) void gather0_kernel(
    const float* __restrict__ feat0e,
    const float* __restrict__ Wg, const float* __restrict__ bg,
    const char* __restrict__ wsp, const _Float16* __restrict__ msg0,
    float* __restrict__ out)
{
    __shared__ float Wgl[2048];
    __shared__ float ag[4][64];
    const int tid = threadIdx.x, w = tid >> 6, lane = tid & 63;
    for (int t = tid; t < 2048; t += 256) Wgl[t] = Wg[t];

    const int n = blockIdx.x * 4 + w;
    const int* rs = (const int*)(wsp + OFF_RS);
    const int i0 = rs[n], i1 = rs[n + 1];
    const int r8 = lane >> 3, c8 = lane & 7;

    float a[8];
#pragma unroll
    for (int j = 0; j < 8; j++) a[j] = 0.f;
    for (int i = i0 + r8; i < i1; i += 8) {
        half8 m = *(const half8*)(msg0 + (size_t)i * 64 + c8 * 8);
#pragma unroll
        for (int j = 0; j < 8; j++) a[j] += (float)m[j];
    }
#pragma unroll
    for (int s = 8; s < 64; s <<= 1)
#pragma unroll
        for (int j = 0; j < 8; j++) a[j] += __shfl_xor(a[j], s);
    if (r8 == 0)
#pragma unroll
        for (int j = 0; j < 8; j++) ag[w][c8 * 8 + j] = a[j];
    __syncthreads();

    const float inv = 1.0f / fmaxf((float)(i1 - i0), 1.0f);
    float av = ag[w][lane] * inv;
    out[(size_t)n * 160 + lane] = silu_f(av) + feat0e[(size_t)n * 64 + lane];

    if (lane < 32) {
        float gs = bg[lane];
#pragma unroll
        for (int p = 0; p < 64; ++p) gs = fmaf(ag[w][p] * inv, Wgl[p * 32 + lane], gs);
        out[(size_t)n * 160 + 64 + lane] = silu_f(gs);   // stash gate
    }
}

// ---------------------------------------------------------------------------
// gather1: per-node sum of msg1 range; finalize out1o with stashed gates.
__global__ __launch_bounds__(256) void gather1_kernel(
    const float* __restrict__ feat1o,
    const char* __restrict__ wsp, const _Float16* __restrict__ msg1,
    float* __restrict__ out)
{
    __shared__ float ag1[4][96];
    __shared__ float gl[4][32];
    const int tid = threadIdx.x, w = tid >> 6, lane = tid & 63;
    const int n = blockIdx.x * 4 + w;
    const int* rs = (const int*)(wsp + OFF_RS);
    const int i0 = rs[n], i1 = rs[n + 1];

    if (lane < 32) gl[w][lane] = out[(size_t)n * 160 + 64 + lane];

    const int r4 = lane >> 4, c12 = lane & 15;
    float a[8];
#pragma unroll
    for (int j = 0; j < 8; j++) a[j] = 0.f;
    if (c12 < 12)
        for (int i = i0 + r4; i < i1; i += 4) {
            half8 m = *(const half8*)(msg1 + (size_t)i * 96 + c12 * 8);
#pragma unroll
            for (int j = 0; j < 8; j++) a[j] += (float)m[j];
        }
#pragma unroll
    for (int s = 16; s < 64; s <<= 1)
#pragma unroll
        for (int j = 0; j < 8; j++) a[j] += __shfl_xor(a[j], s);
    if (r4 == 0 && c12 < 12)
#pragma unroll
        for (int j = 0; j < 8; j++) ag1[w][c12 * 8 + j] = a[j];
    __syncthreads();

    const float inv = 1.0f / fmaxf((float)(i1 - i0), 1.0f);
#pragma unroll
    for (int t = 0; t < 2; t++) {
        int idx = t * 64 + lane;
        if (idx < 96) {
            int c = idx / 3, x = idx - 3 * c;
            float v = ag1[w][x * 32 + c] * inv * gl[w][c] + feat1o[(size_t)n * 96 + idx];
            out[(size_t)n * 160 + 64 + idx] = v;
        }
    }
}

// ---------------------------------------------------------------------------
// Fallback (round-1 monolithic VALU kernel) + node kernel, for small ws_size.
__global__ __launch_bounds__(256) void edge_kernel_fb(
    const float* __restrict__ feat0e, const float* __restrict__ feat1o,
    const float* __restrict__ edge_attr, const float* __restrict__ pos,
    const int* __restrict__ eidx,
    const float* __restrict__ W1, const float* __restrict__ b1,
    const float* __restrict__ W2, const float* __restrict__ b2,
    const float* __restrict__ W3, const float* __restrict__ b3,
    const float* __restrict__ wss, const float* __restrict__ wvv,
    const float* __restrict__ wsv, const float* __restrict__ wvs,
    const float* __restrict__ wcross,
    const int* __restrict__ i64flag,
    float* __restrict__ out, float* __restrict__ counts)
{
    const int e = blockIdx.x * 256 + threadIdx.x;
    int src, dst;
    if (*i64flag) { src = (int)((const long long*)eidx)[e]; dst = (int)((const long long*)eidx)[EE + e]; }
    else          { src = eidx[e];                          dst = eidx[EE + e]; }
    const float rel0 = pos[dst * 3 + 0] - pos[src * 3 + 0];
    const float rel1 = pos[dst * 3 + 1] - pos[src * 3 + 1];
    const float rel2 = pos[dst * 3 + 2] - pos[src * 3 + 2];
    float h1[HH];
#pragma unroll
    for (int j = 0; j < HH; ++j) h1[j] = b1[j];
    for (int i = 0; i < HH; ++i) {
        float a = edge_attr[(size_t)e * HH + i];
        const float* ww = W1 + i * HH;
#pragma unroll
        for (int j = 0; j < HH; ++j) h1[j] = fmaf(a, ww[j], h1[j]);
    }
#pragma unroll
    for (int j = 0; j < HH; ++j) h1[j] = silu_f(h1[j]);
    float h2[HH];
#pragma unroll
    for (int j = 0; j < HH; ++j) h2[j] = b2[j];
#pragma unroll
    for (int i = 0; i < HH; ++i) {
        float a = h1[i];
        const float* ww = W2 + i * HH;
#pragma unroll
        for (int j = 0; j < HH; ++j) h2[j] = fmaf(a, ww[j], h2[j]);
    }
#pragma unroll
    for (int j = 0; j < HH; ++j) h2[j] = silu_f(h2[j]);
    float es[HH];
#pragma unroll
    for (int j = 0; j < HH; ++j) es[j] = b3[j];
#pragma unroll
    for (int i = 0; i < HH; ++i) {
        float a = h2[i];
        const float* ww = W3 + i * HH;
#pragma unroll
        for (int j = 0; j < HH; ++j) es[j] = fmaf(a, ww[j], es[j]);
    }
    float dotv[D1];
#pragma unroll
    for (int d = 0; d < D1; ++d) {
        float v0 = feat1o[(size_t)src * 96 + d * 3 + 0];
        float v1 = feat1o[(size_t)src * 96 + d * 3 + 1];
        float v2 = feat1o[(size_t)src * 96 + d * 3 + 2];
        dotv[d] = fmaf(v0, rel0, fmaf(v1, rel1, v2 * rel2));
    }
#pragma unroll
    for (int ob = 0; ob < 4; ++ob) {
        const int o0 = ob * 16;
        float acc[16];
#pragma unroll
        for (int j = 0; j < 16; ++j) acc[j] = 0.f;
#pragma unroll
        for (int d = 0; d < D1; ++d) {
            const float* ww = wvv + d * D0 + o0;
#pragma unroll
            for (int j = 0; j < 16; ++j) acc[j] = fmaf(dotv[d], ww[j], acc[j]);
        }
        for (int p = 0; p < D0; ++p) {
            float sval = feat0e[(size_t)src * D0 + p];
            const float* wp = wss + (size_t)p * HH * D0 + o0;
#pragma unroll
            for (int h = 0; h < HH; ++h) {
                float c = sval * es[h];
                const float* ww = wp + h * D0;
#pragma unroll
                for (int j = 0; j < 16; ++j) acc[j] = fmaf(c, ww[j], acc[j]);
            }
        }
        float* obase = out + (size_t)dst * 160 + o0;
#pragma unroll
        for (int j = 0; j < 16; ++j) atomicAdd(obase + j, acc[j]);
    }
    atomicAdd(counts + dst, 1.0f);
    float g[D1];
#pragma unroll
    for (int c = 0; c < D1; ++c) g[c] = 0.f;
    for (int p = 0; p < D0; ++p) {
        float sval = feat0e[(size_t)src * D0 + p];
        const float* ww = wsv + p * D1;
#pragma unroll
        for (int c = 0; c < D1; ++c) g[c] = fmaf(sval, ww[c], g[c]);
    }
    float acc1[D1 * 3];
#pragma unroll
    for (int c = 0; c < D1; ++c) {
        acc1[c * 3 + 0] = g[c] * rel0;
        acc1[c * 3 + 1] = g[c] * rel1;
        acc1[c * 3 + 2] = g[c] * rel2;
    }
    for (int d = 0; d < D1; ++d) {
        float v0 = feat1o[(size_t)src * 96 + d * 3 + 0];
        float v1 = feat1o[(size_t)src * 96 + d * 3 + 1];
        float v2 = feat1o[(size_t)src * 96 + d * 3 + 2];
        float cx0 = fmaf(v1, rel2, -v2 * rel1);
        float cx1 = fmaf(v2, rel0, -v0 * rel2);
        float cx2 = fmaf(v0, rel1, -v1 * rel0);
        const float* wd = wvs + (size_t)d * HH * D1;
        const float* wc = wcross + d * D1;
#pragma unroll
        for (int cb = 0; cb < 2; ++cb) {
            float t[16];
#pragma unroll
            for (int cc = 0; cc < 16; ++cc) t[cc] = 0.f;
#pragma unroll
            for (int h = 0; h < HH; ++h) {
                const float* ww = wd + h * D1 + cb * 16;
                float ev = es[h];
#pragma unroll
                for (int cc = 0; cc < 16; ++cc) t[cc] = fmaf(ev, ww[cc], t[cc]);
            }
#pragma unroll
            for (int cc = 0; cc < 16; ++cc) {
                int c = cb * 16 + cc;
                float tc = t[cc], wcc = wc[c];
                acc1[c * 3 + 0] = fmaf(v0, tc, fmaf(cx0, wcc, acc1[c * 3 + 0]));
                acc1[c * 3 + 1] = fmaf(v1, tc, fmaf(cx1, wcc, acc1[c * 3 + 1]));
                acc1[c * 3 + 2] = fmaf(v2, tc, fmaf(cx2, wcc, acc1[c * 3 + 2]));
            }
        }
    }
    float* obase1 = out + (size_t)dst * 160 + 64;
#pragma unroll
    for (int k = 0; k < D1 * 3; ++k) atomicAdd(obase1 + k, acc1[k]);
}

__global__ __launch_bounds__(256) void node_kernel_fb(
    const float* __restrict__ feat0e,
    const float* __restrict__ feat1o,
    const float* __restrict__ Wg, const float* __restrict__ bg,
    const float* __restrict__ counts,
    float* __restrict__ out)
{
    const int w = threadIdx.x >> 6;
    const int n = blockIdx.x * 4 + w;
    const int lane = threadIdx.x & 63;
    __shared__ float a_lds[4][D0];
    __shared__ float gate_lds[4][D1];

    const float inv = 1.0f / fmaxf(counts[n], 1.0f);
    float a = out[(size_t)n * 160 + lane] * inv;
    a_lds[w][lane] = a;
    __syncthreads();

    out[(size_t)n * 160 + lane] = silu_f(a) + feat0e[(size_t)n * D0 + lane];

    if (lane < D1) {
        float gs = bg[lane];
        for (int p = 0; p < D0; ++p) gs = fmaf(a_lds[w][p], Wg[p * D1 + lane], gs);
        gate_lds[w][lane] = silu_f(gs);
    }
    __syncthreads();

    for (int idx = lane; idx < D1 * 3; idx += 64) {
        int c = idx / 3;
        size_t o = (size_t)n * 160 + 64 + idx;
        out[o] = fmaf(out[o] * inv, gate_lds[w][c], feat1o[(size_t)n * (D1 * 3) + idx]);
    }
}

// ---------------------------------------------------------------------------
extern "C" void kernel_launch(void* const* d_in, const int* in_sizes, int n_in,
                              void* d_out, int out_size, void* d_ws, size_t ws_size,
                              hipStream_t stream) {
    const float* feat0e    = (const float*)d_in[0];
    const float* feat1o    = (const float*)d_in[1];
    const float* edge_attr = (const float*)d_in[2];
    const float* pos       = (const float*)d_in[3];
    const int*   eidx      = (const int*)d_in[4];
    const float* W1 = (const float*)d_in[5];
    const float* b1 = (const float*)d_in[6];
    const float* W2 = (const float*)d_in[7];
    const float* b2 = (const float*)d_in[8];
    const float* W3 = (const float*)d_in[9];
    const float* b3 = (const float*)d_in[10];
    const float* wss    = (const float*)d_in[11];
    const float* wvv    = (const float*)d_in[12];
    const float* wsv    = (const float*)d_in[13];
    const float* wvs    = (const float*)d_in[14];
    const float* wcross = (const float*)d_in[15];
    const float* Wg = (const float*)d_in[16];
    const float* bg = (const float*)d_in[17];

    float* out = (float*)d_out;
    char*  ws  = (char*)d_ws;
    int* hist = (int*)(ws + OFF_HIST);
    int* rs   = (int*)(ws + OFF_RS);
    int* cur  = (int*)(ws + OFF_CUR);
    int* flag = (int*)(ws + OFF_FLAG);

    detect_idx_kernel<<<1, 1, 0, stream>>>(eidx, flag);

    if (ws_size >= WS_NEED) {
        int* srca = (int*)(ws + OFF_SRCA);
        int* dsta = (int*)(ws + OFF_DSTA);
        int* pe   = (int*)(ws + OFF_PE);
        _Float16* msg = (_Float16*)(ws + OFF_MSG);

        hipMemsetAsync(ws + OFF_HIST, 0, NN * sizeof(int), stream);
        hist_kernel<<<EE / 256, 256, 0, stream>>>(eidx, flag, hist);
        scan_kernel<<<1, 1024, 0, stream>>>(hist, rs, cur);
        scatter_kernel<<<EE / 256, 256, 0, stream>>>(eidx, flag, cur, srca, dsta, pe);
        prep_kernel<<<169, 256, 0, stream>>>(wss, wvv, wsv, wvs, wcross, W1, W2, W3, ws);

        msg0e_kernel<<<EE / 256, 256, 0, stream>>>(
            feat0e, feat1o, edge_attr, pos, b1, b2, b3, (const char*)ws, msg);
        gather0_kernel<<<NN / 4, 256, 0, stream>>>(
            feat0e, Wg, bg, (const char*)ws, msg, out);
        msg1o_kernel<<<EE / 256, 256, 0, stream>>>(
            feat0e, feat1o, edge_attr, pos, b1, b2, b3, (const char*)ws, msg);
        gather1_kernel<<<NN / 4, 256, 0, stream>>>(
            feat1o, (const char*)ws, msg, out);
    } else {
        float* counts = (float*)(ws + OFF_HIST);
        hipMemsetAsync(d_out, 0, (size_t)out_size * sizeof(float), stream);
        hipMemsetAsync(ws + OFF_HIST, 0, NN * sizeof(float), stream);
        edge_kernel_fb<<<EE / 256, 256, 0, stream>>>(
            feat0e, feat1o, edge_attr, pos, eidx,
            W1, b1, W2, b2, W3, b3, wss, wvv, wsv, wvs, wcross,
            flag, out, counts);
        node_kernel_fb<<<NN / 4, 256, 0, stream>>>(feat0e, feat1o, Wg, bg, counts, out);
    }
}